// Round 8
// baseline (427.661 us; speedup 1.0000x reference)
//
#include <hip/hip_runtime.h>

typedef unsigned short u16;
typedef __bf16 bf16x8 __attribute__((ext_vector_type(8)));
typedef short s16x4 __attribute__((ext_vector_type(4)));
typedef short s16x8 __attribute__((ext_vector_type(8)));
typedef float f32x4 __attribute__((ext_vector_type(4)));

#define S_LEN 2048
#define NHEAD 16
#define QHEAD 192
#define EPS 1e-6f
#define ATTN_SCALE 0.07216878364870323f   /* 192^-0.5 */
#define QSCALE_LOG2E 0.10412011228586118f /* ATTN_SCALE * log2(e) */

__device__ __forceinline__ u16 f2bf(float f) {
    unsigned u = __builtin_bit_cast(unsigned, f);
    u = (u + 0x7FFFu + ((u >> 16) & 1u)) >> 16;
    return (u16)u;
}
__device__ __forceinline__ float bf2f(u16 h) {
    unsigned u = ((unsigned)h) << 16;
    return __builtin_bit_cast(float, u);
}

__device__ __forceinline__ void gl_lds16(const u16* g, u16* l) {
    __builtin_amdgcn_global_load_lds(
        (const __attribute__((address_space(1))) unsigned int*)g,
        (__attribute__((address_space(3))) unsigned int*)l,
        16, 0, 0);
}

#if defined(__has_builtin) && __has_builtin(__builtin_amdgcn_mfma_f32_16x16x16bf16_1k)
__device__ __forceinline__ f32x4 mfma16(s16x4 a, s16x4 b, f32x4 c) {
    return __builtin_amdgcn_mfma_f32_16x16x16bf16_1k(a, b, c, 0, 0, 0);
}
#else
__device__ __forceinline__ f32x4 mfma16(s16x4 a, s16x4 b, f32x4 c) {
    asm volatile("v_mfma_f32_16x16x16_bf16 %0, %1, %2, %0"
                 : "+v"(c) : "v"(a), "v"(b));
    return c;
}
#endif

// ---------------------------------------------------------------------------
// bf16 GEMM core:  C[M][N] = A[M][K] @ Bt[N][K]^T
// 4-wave (256-thread) blocks, 128x128 tile, wave-tile 64x64 (16 MFMA / 8
// ds_read_b128 = ratio 2.0; round-7's 8-wave 64x32 was 8/6 = 1.33).
// Round-7 post-mortem: LDS-read-throughput-bound - 48KB LDS reads per
// block-iter at ~85 B/cyc/CU was ~1600 cyc vs 160 cyc of MFMA. This cuts
// LDS bytes per tile-step 48->32KB. Keeps the counted-vmcnt depth-2
// pipeline (T4): stage t+2 (4 loads/wave), compute t, wait vmcnt(4)
// (leaves t+2's loads in flight) + raw s_barrier, sched_barrier fences.
// LDS 3 x 16KB = 48KB. Buffer select by offset arithmetic (gfx950
// addrspace-select miscompile with ternary LDS pointers into gl_lds).
// ---------------------------------------------------------------------------
template <int CF32>
__device__ __forceinline__ void gemm_core(
    u16* __restrict__ smem,
    const u16* __restrict__ A, const u16* __restrict__ B, void* __restrict__ Cv,
    int K, int lda, int ldb, int ldc, int tm, int tn)
{
    const int tid = threadIdx.x;
    const int w = tid >> 6, lane = tid & 63;
    const int q = lane >> 4, r = lane & 15;

    const int lr = lane & 15;
    const int lc = (lane >> 4) * 8;
    // wave w stages A rows [w*32, w*32+32) and B rows [w*32, w*32+32)
    const u16* ga0 = A + (long)(tm * 128 + w * 32 + lr) * lda + lc;
    const u16* ga1 = ga0 + 16 * (long)lda;
    const u16* gb0 = B + (long)(tn * 128 + w * 32 + lr) * ldb + lc;
    const u16* gb1 = gb0 + 16 * (long)ldb;
    const int sa0 = w * 1024, sa1 = sa0 + 512;
    const int sb0 = 4096 + w * 1024, sb1 = sb0 + 512;
    // buffer = 8192 u16 (16KB): A chunks [0,4096), B chunks [4096,8192)

    f32x4 acc[4][4] = {};
    const int wm = w >> 1;      // 64-row half
    const int wn = w & 1;       // 64-col half
    const int n = K >> 5;

    // prologue: stage iters 0 and 1 (8 loads/wave)
    gl_lds16(ga0, smem + sa0);
    gl_lds16(ga1, smem + sa1);
    gl_lds16(gb0, smem + sb0);
    gl_lds16(gb1, smem + sb1);
    gl_lds16(ga0 + 32, smem + 8192 + sa0);
    gl_lds16(ga1 + 32, smem + 8192 + sa1);
    gl_lds16(gb0 + 32, smem + 8192 + sb0);
    gl_lds16(gb1 + 32, smem + 8192 + sb1);
    asm volatile("s_waitcnt vmcnt(4)" ::: "memory");   // iter-0's 4 landed
    __builtin_amdgcn_sched_barrier(0);
    __builtin_amdgcn_s_barrier();
    __builtin_amdgcn_sched_barrier(0);

    int bc = 0;   // t % 3
    for (int t = 0; t < n; ++t) {
        u16* const cur = smem + bc * 8192;
        if (t + 2 < n) {        // stage iter t+2 (buffer last read at t-1)
            int bn = bc + 2; if (bn >= 3) bn -= 3;
            u16* const nxt = smem + bn * 8192;
            const long k2 = (long)(t + 2) << 5;
            gl_lds16(ga0 + k2, nxt + sa0);
            gl_lds16(ga1 + k2, nxt + sa1);
            gl_lds16(gb0 + k2, nxt + sb0);
            gl_lds16(gb1 + k2, nxt + sb1);
        }
        bf16x8 af[4], bv[4];
        #pragma unroll
        for (int mt = 0; mt < 4; ++mt)
            af[mt] = *(const bf16x8*)&cur[(wm * 4 + mt) * 512 + lane * 8];
        #pragma unroll
        for (int nt = 0; nt < 4; ++nt)
            bv[nt] = *(const bf16x8*)&cur[4096 + (wn * 4 + nt) * 512 + lane * 8];
        #pragma unroll
        for (int mt = 0; mt < 4; ++mt)
            #pragma unroll
            for (int nt = 0; nt < 4; ++nt)
                acc[mt][nt] = __builtin_amdgcn_mfma_f32_16x16x32_bf16(
                    af[mt], bv[nt], acc[mt][nt], 0, 0, 0);
        if (t + 1 < n) {
            if (t + 2 < n) asm volatile("s_waitcnt vmcnt(4)" ::: "memory");
            else           asm volatile("s_waitcnt vmcnt(0)" ::: "memory");
            __builtin_amdgcn_sched_barrier(0);
            __builtin_amdgcn_s_barrier();
            __builtin_amdgcn_sched_barrier(0);
        }
        if (++bc == 3) bc = 0;
    }

    const int row0 = tm * 128 + wm * 64 + q * 4;
    const int col0 = tn * 128 + wn * 64 + r;
    if (CF32) {
        float* C = (float*)Cv;
        #pragma unroll
        for (int mt = 0; mt < 4; ++mt)
            #pragma unroll
            for (int i = 0; i < 4; ++i) {
                long rb = (long)(row0 + mt * 16 + i) * ldc + col0;
                #pragma unroll
                for (int nt = 0; nt < 4; ++nt)
                    C[rb + nt * 16] = acc[mt][nt][i];
            }
    } else {
        u16* C = (u16*)Cv;
        #pragma unroll
        for (int mt = 0; mt < 4; ++mt)
            #pragma unroll
            for (int i = 0; i < 4; ++i) {
                long rb = (long)(row0 + mt * 16 + i) * ldc + col0;
                #pragma unroll
                for (int nt = 0; nt < 4; ++nt)
                    C[rb + nt * 16] = f2bf(acc[mt][nt][i]);
            }
    }
}

template <int CF32>
__global__ __launch_bounds__(256, 2)
void gemm_bt(const u16* __restrict__ A, const u16* __restrict__ B,
             void* __restrict__ Cv, int K, int lda, int ldb, int ldc)
{
    __shared__ __align__(16) u16 smem[3 * 8192];
    gemm_core<CF32>(smem, A, B, Cv, K, lda, ldb, ldc, blockIdx.y, blockIdx.x);
}

// Two independent GEMMs in ONE dispatch (z selects). Early-exit blocks
// return before any barrier (block-uniform - no hang).
__global__ __launch_bounds__(256, 2)
void gemm_bt_dual(const u16* __restrict__ A0, const u16* __restrict__ B0,
                  void* __restrict__ C0, int K0, int lda0, int ldb0, int ldc0, int nx0,
                  const u16* __restrict__ A1, const u16* __restrict__ B1,
                  void* __restrict__ C1, int K1, int lda1, int ldb1, int ldc1, int nx1)
{
    __shared__ __align__(16) u16 smem[3 * 8192];
    if (blockIdx.z == 0) {
        if ((int)blockIdx.x >= nx0) return;
        gemm_core<0>(smem, A0, B0, C0, K0, lda0, ldb0, ldc0, blockIdx.y, blockIdx.x);
    } else {
        if ((int)blockIdx.x >= nx1) return;
        gemm_core<0>(smem, A1, B1, C1, K1, lda1, ldb1, ldc1, blockIdx.y, blockIdx.x);
    }
}

// ---------------------------------------------------------------------------
// Flash attention, S^T formulation, double-buffered prefetch pipeline.
// Block = 128 threads (2 waves); wave w owns 32 q rows as two 16-col
// n-blocks (Qf[2][6], Oacc[8][2]) -> each K/V ds_read feeds TWO q-blocks,
// halving LDS-read bytes per block-tile vs the 4-wave/16-q-rows version
// (round-7 counters showed flash ~LDS-read-bound: 160KB/tile at 85 B/cyc).
// kv-tile 64; LDS 2 x 40KB = 80KB -> 2 blocks/CU.
// PV reads are conflict-free ds_read_b128 via the s-permuted vt layout.
// Maxless exp2-domain softmax (query pre-scaled by SCALE*log2e).
// Grid: 1D 512, complementary pairing (b, b+256 share a CU).
// ---------------------------------------------------------------------------
template<int C0, int C1>
__device__ __forceinline__ void stage_tile(
    const u16* __restrict__ kvb, const u16* __restrict__ kpe,
    const u16* __restrict__ vt,
    u16* __restrict__ Kl, u16* __restrict__ Vl,
    int h, int t, int quad, int r)
{
    #pragma unroll
    for (int c = C0; c < C1; ++c) {
        if (c < 24) {
            const int mtk = c / 6, kc = c % 6;
            const int row = t * 64 + mtk * 16 + r;
            const u16* src = (kc < 4)
                ? kvb + (size_t)row * 4096 + h * 256 + kc * 32 + quad * 8
                : kpe + (size_t)row * 64 + (kc - 4) * 32 + quad * 8;
            gl_lds16(src, &Kl[c * 512]);
        } else {
            const int cv = c - 24, mtd = cv >> 1, sc = cv & 1;
            const u16* src = vt + ((size_t)h * 128 + mtd * 16 + r) * 2048
                             + t * 64 + sc * 32 + quad * 8;
            gl_lds16(src, &Vl[cv * 512]);
        }
    }
}

__device__ __forceinline__ void stage_dispatch(
    const u16* __restrict__ kvb, const u16* __restrict__ kpe,
    const u16* __restrict__ vt,
    u16* __restrict__ Kl, u16* __restrict__ Vl,
    int w, int h, int t, int quad, int r)
{
    if (w == 0) stage_tile<0, 20>(kvb, kpe, vt, Kl, Vl, h, t, quad, r);
    else        stage_tile<20, 40>(kvb, kpe, vt, Kl, Vl, h, t, quad, r);
}

__device__ __forceinline__ void kv_tile_step(
    const u16* __restrict__ Kl, const u16* __restrict__ Vl,
    const bf16x8 (&Qf)[2][6], f32x4 (&Oacc)[8][2], float (&lsum)[2],
    int lane, int quad, int r, int kglob0, int qg0, int qg1, bool maskT)
{
    f32x4 Sacc[4][2];
    #pragma unroll
    for (int mtk = 0; mtk < 4; ++mtk) {
        Sacc[mtk][0] = (f32x4){0.f, 0.f, 0.f, 0.f};
        Sacc[mtk][1] = (f32x4){0.f, 0.f, 0.f, 0.f};
    }
    #pragma unroll
    for (int kc = 0; kc < 6; ++kc)
        #pragma unroll
        for (int mtk = 0; mtk < 4; ++mtk) {
            bf16x8 Ak = *(const bf16x8*)&Kl[(mtk * 6 + kc) * 512 + lane * 8];
            Sacc[mtk][0] = __builtin_amdgcn_mfma_f32_16x16x32_bf16(
                Ak, Qf[0][kc], Sacc[mtk][0], 0, 0, 0);
            Sacc[mtk][1] = __builtin_amdgcn_mfma_f32_16x16x32_bf16(
                Ak, Qf[1][kc], Sacc[mtk][1], 0, 0, 0);
        }
    #pragma unroll
    for (int sc = 0; sc < 2; ++sc) {
        s16x4 Pf[2][2];
        #pragma unroll
        for (int nn = 0; nn < 2; ++nn) {
            const int qg = nn ? qg1 : qg0;
            #pragma unroll
            for (int half = 0; half < 2; ++half) {
                const int kb = sc * 2 + half;
                const int kb0 = kglob0 + kb * 16 + quad * 4;
                #pragma unroll
                for (int i = 0; i < 4; ++i) {
                    float pv = exp2f(Sacc[kb][nn][i]);
                    if (maskT && (kb0 + i > qg)) pv = 0.f;
                    lsum[nn] += pv;
                    Pf[nn][half][i] = (short)f2bf(pv);
                }
            }
        }
        #pragma unroll
        for (int mtd = 0; mtd < 8; ++mtd) {
            s16x8 Av8 = *(const s16x8*)&Vl[(mtd * 2 + sc) * 512 + quad * 128 + r * 8];
            s16x4 lo = __builtin_shufflevector(Av8, Av8, 0, 1, 2, 3);
            s16x4 hi = __builtin_shufflevector(Av8, Av8, 4, 5, 6, 7);
            Oacc[mtd][0] = mfma16(lo, Pf[0][0], Oacc[mtd][0]);
            Oacc[mtd][0] = mfma16(hi, Pf[0][1], Oacc[mtd][0]);
            Oacc[mtd][1] = mfma16(lo, Pf[1][0], Oacc[mtd][1]);
            Oacc[mtd][1] = mfma16(hi, Pf[1][1], Oacc[mtd][1]);
        }
    }
}

__global__ __launch_bounds__(128, 1)
void flash_attn(const u16* __restrict__ query, const u16* __restrict__ kvb,
                const u16* __restrict__ kpe, const u16* __restrict__ vt,
                u16* __restrict__ ao)
{
    const int tid = threadIdx.x;
    const int w = tid >> 6, lane = tid & 63;
    const int quad = lane >> 4, r = lane & 15;

    const int bid = (int)blockIdx.x;
    const int i = bid & 255;
    const int t_ = i >> 4;
    const int h = i & 15;
    const int j = (bid < 256) ? (31 - t_) : t_;

    const int q0 = j * 64;
    const int ntk = j + 1;

    __shared__ __align__(16) u16 smem[40960];   // 80KB: two 40KB tile buffers
    // buffer b at smem + b*20480: K = [0,12288) u16, V = [12288,20480) u16

    const int qg0 = q0 + w * 32 + r;
    const int qg1 = qg0 + 16;

    bf16x8 Qf[2][6];
    #pragma unroll
    for (int nn = 0; nn < 2; ++nn)
        #pragma unroll
        for (int kc = 0; kc < 6; ++kc)
            Qf[nn][kc] = *(const bf16x8*)(query
                + ((size_t)h * S_LEN + q0 + w * 32 + nn * 16 + r) * QHEAD
                + kc * 32 + quad * 8);

    f32x4 Oacc[8][2];
    #pragma unroll
    for (int mtd = 0; mtd < 8; ++mtd) {
        Oacc[mtd][0] = (f32x4){0.f, 0.f, 0.f, 0.f};
        Oacc[mtd][1] = (f32x4){0.f, 0.f, 0.f, 0.f};
    }
    float lsum[2] = {0.f, 0.f};

    // prologue: stage tile 0 into buffer 0
    stage_dispatch(kvb, kpe, vt, smem, smem + 12288, w, h, 0, quad, r);
    __syncthreads();

    for (int t = 0; t < ntk; ++t) {
        u16* const curb = smem + (t & 1) * 20480;          // offset arith,
        u16* const nxtb = smem + ((t + 1) & 1) * 20480;    // no ptr select
        if (t + 1 < ntk)
            stage_dispatch(kvb, kpe, vt, nxtb, nxtb + 12288, w, h, t + 1, quad, r);
        kv_tile_step(curb, curb + 12288, Qf, Oacc, lsum,
                     lane, quad, r, t * 64, qg0, qg1, t == ntk - 1);
        __syncthreads();
    }

    #pragma unroll
    for (int nn = 0; nn < 2; ++nn) {
        float l = lsum[nn];
        l += __shfl_xor(l, 16, 64);
        l += __shfl_xor(l, 32, 64);
        const float inv = 1.0f / l;
        const int qrow = q0 + w * 32 + nn * 16 + r;
        #pragma unroll
        for (int mtd = 0; mtd < 8; ++mtd) {
            ushort4 o;
            o.x = f2bf(Oacc[mtd][nn][0] * inv);
            o.y = f2bf(Oacc[mtd][nn][1] * inv);
            o.z = f2bf(Oacc[mtd][nn][2] * inv);
            o.w = f2bf(Oacc[mtd][nn][3] * inv);
            *(ushort4*)(ao + (size_t)qrow * 2048 + h * 128 + mtd * 16 + quad * 4) = o;
        }
    }
}

// ---------------------------------------------------------------------------
// prep_k: fused input-convert + 5 weight transposes (was 6 dispatches).
// Flattened 1D grid of 19200 blocks x 256 threads; branches block-uniform.
// Regions: [0,4096) cvt; then wtrans regions (bx = k-tile, by = n-tile):
//   q_a_w 64x48, kv_a_w 64x20, q_b_w 48x96, kv_b_w 16x128, o_w 64x64.
// ---------------------------------------------------------------------------
__device__ __forceinline__ void wtrans_body(
    float (*tile)[33], const float* __restrict__ in, u16* __restrict__ out,
    int K, int N, int bx, int by, int tid)
{
    const int tx = tid & 31, ty = tid >> 5;   // 32 x 8
    const int k0 = bx * 32, n0 = by * 32;
    #pragma unroll
    for (int jj = 0; jj < 32; jj += 8) {
        int nn = n0 + tx;
        tile[ty + jj][tx] = (nn < N) ? in[(long)(k0 + ty + jj) * N + nn] : 0.0f;
    }
    __syncthreads();
    #pragma unroll
    for (int jj = 0; jj < 32; jj += 8)
        out[(long)(n0 + ty + jj) * K + k0 + tx] = f2bf(tile[tx][ty + jj]);
}

__global__ __launch_bounds__(256)
void prep_k(const float4* __restrict__ x4, ushort4* __restrict__ xb4,
            const float* __restrict__ q_a_w, const float* __restrict__ kv_a_w,
            const float* __restrict__ q_b_w, const float* __restrict__ kv_b_w,
            const float* __restrict__ o_w,
            u16* __restrict__ W1, u16* __restrict__ qbwt,
            u16* __restrict__ kvbwt, u16* __restrict__ owt)
{
    __shared__ float tile[32][33];
    const int tid = threadIdx.x;
    int b = (int)blockIdx.x;
    if (b < 4096) {
        int i = b * 256 + tid;     // exactly 1048576 float4s
        float4 v = x4[i];
        ushort4 o;
        o.x = f2bf(v.x); o.y = f2bf(v.y); o.z = f2bf(v.z); o.w = f2bf(v.w);
        xb4[i] = o;
        return;
    }
    b -= 4096;
    if (b < 3072)       wtrans_body(tile, q_a_w,  W1,                  2048, 1536, b % 64, b / 64, tid);
    else if ((b -= 3072) < 1280) wtrans_body(tile, kv_a_w, W1 + 1536ULL * 2048, 2048, 576,  b % 64, b / 64, tid);
    else if ((b -= 1280) < 4608) wtrans_body(tile, q_b_w,  qbwt,       1536, 3072, b % 48, b / 48, tid);
    else if ((b -= 4608) < 2048) wtrans_body(tile, kv_b_w, kvbwt,      512,  4096, b % 16, b / 16, tid);
    else { b -= 2048;            wtrans_body(tile, o_w,    owt,        2048, 2048, b % 64, b / 64, tid); }
}

// ---------------------------------------------------------------------------
// norm_k: fused q_a rmsnorm (1536 cols, in-place) + kv_a norm/rope/cache.
// One block per sequence row.
// ---------------------------------------------------------------------------
__global__ __launch_bounds__(256)
void norm_k(u16* __restrict__ qkv, const float* __restrict__ q_ln,
            const float* __restrict__ kv_ln, const int* __restrict__ pos_ids,
            const float* __restrict__ cosb, const float* __restrict__ sinb,
            float* __restrict__ kvout, u16* __restrict__ cnb,
            u16* __restrict__ kpe)
{
    const int s = blockIdx.x, tid = threadIdx.x;
    u16* row = qkv + (long)s * 2176;
    u16* row2 = row + 1536;
    __shared__ float red[8];
    float sum = 0.f;
    for (int d = tid; d < 1536; d += 256) { float v = bf2f(row[d]); sum += v * v; }
    #pragma unroll
    for (int o = 32; o; o >>= 1) sum += __shfl_xor(sum, o, 64);
    if ((tid & 63) == 0) red[tid >> 6] = sum;
    float sum2 = 0.f;
    for (int d = tid; d < 512; d += 256) { float v = bf2f(row2[d]); sum2 += v * v; }
    #pragma unroll
    for (int o = 32; o; o >>= 1) sum2 += __shfl_xor(sum2, o, 64);
    if ((tid & 63) == 0) red[4 + (tid >> 6)] = sum2;
    __syncthreads();
    sum  = red[0] + red[1] + red[2] + red[3];
    sum2 = red[4] + red[5] + red[6] + red[7];
    const float sc1 = rsqrtf(sum / 1536.f + EPS);
    const float sc2 = rsqrtf(sum2 / 512.f + EPS);
    for (int d = tid; d < 1536; d += 256)
        row[d] = f2bf(bf2f(row[d]) * sc1 * q_ln[d]);
    for (int d = tid; d < 512; d += 256) {
        float v = bf2f(row2[d]) * sc2 * kv_ln[d];
        kvout[(long)s * 576 + d] = v;
        cnb[(long)s * 512 + d] = f2bf(v);
    }
    if (tid < 32) {
        int p = pos_ids[s];
        float x0 = bf2f(row2[512 + 2 * tid]);
        float x1 = bf2f(row2[512 + 2 * tid + 1]);
        float c1 = cosb[p * 64 + tid], s1 = sinb[p * 64 + tid];
        float c2 = cosb[p * 64 + 32 + tid], s2 = sinb[p * 64 + 32 + tid];
        float lo = x0 * c1 - x1 * s1;
        float hi = x1 * c2 + x0 * s2;
        kvout[(long)s * 576 + 512 + tid] = lo;
        kvout[(long)s * 576 + 544 + tid] = hi;
        kpe[(long)s * 64 + tid] = f2bf(lo);
        kpe[(long)s * 64 + 32 + tid] = f2bf(hi);
    }
}

// ---------------------------------------------------------------------------
// post_k: fused qrope ([0,2048) blocks) + vtrans ([2048,6144) blocks).
// vtrans s-axis permuted within 32-blocks so flash PV reads b128:
// new position quad*8 + half*4 + i  <->  s = half*16 + quad*4 + i.
// ---------------------------------------------------------------------------
__global__ __launch_bounds__(256)
void post_k(const u16* __restrict__ qb, const int* __restrict__ pos_ids,
            const float* __restrict__ cosb, const float* __restrict__ sinb,
            u16* __restrict__ query, const u16* __restrict__ kv,
            u16* __restrict__ vt)
{
    __shared__ u16 tile[32][33];
    const int tid = threadIdx.x;
    int b = (int)blockIdx.x;
    if (b < 2048) {
        const int s = b;
        const u16* row = qb + (long)s * 3072;
        {   // nope part: 16 heads x 16 chunks of 8, scaled
            int h = tid >> 4, c = tid & 15;
            const u16* src = &row[h * QHEAD + c * 8];
            u16* dst = &query[((long)(h * S_LEN + s)) * QHEAD + c * 8];
            ushort4 a = *(const ushort4*)src;
            ushort4 bb = *(const ushort4*)(src + 4);
            ushort4 oa, ob;
            oa.x = f2bf(bf2f(a.x) * QSCALE_LOG2E); oa.y = f2bf(bf2f(a.y) * QSCALE_LOG2E);
            oa.z = f2bf(bf2f(a.z) * QSCALE_LOG2E); oa.w = f2bf(bf2f(a.w) * QSCALE_LOG2E);
            ob.x = f2bf(bf2f(bb.x) * QSCALE_LOG2E); ob.y = f2bf(bf2f(bb.y) * QSCALE_LOG2E);
            ob.z = f2bf(bf2f(bb.z) * QSCALE_LOG2E); ob.w = f2bf(bf2f(bb.w) * QSCALE_LOG2E);
            *(ushort4*)dst = oa;
            *(ushort4*)(dst + 4) = ob;
        }
        int p = pos_ids[s];
        for (int idx = tid; idx < 512; idx += 256) {
            int h = idx >> 5, i = idx & 31;
            float x0 = bf2f(row[h * QHEAD + 128 + 2 * i]);
            float x1 = bf2f(row[h * QHEAD + 128 + 2 * i + 1]);
            float c1 = cosb[p * 64 + i], s1 = sinb[p * 64 + i];
            float c2 = cosb[p * 64 + 32 + i], s2 = sinb[p * 64 + 32 + i];
            u16* qr = query + ((long)(h * S_LEN + s)) * QHEAD;
            qr[128 + i] = f2bf((x0 * c1 - x1 * s1) * QSCALE_LOG2E);
            qr[160 + i] = f2bf((x1 * c2 + x0 * s2) * QSCALE_LOG2E);
        }
    } else {
        b -= 2048;
        const int s0 = (b & 63) * 32, d0 = ((b >> 6) & 3) * 32, h = b >> 8;
        const int tx = tid & 31, ty = tid >> 5;
        #pragma unroll
        for (int jj = 0; jj < 32; jj += 8)
            tile[ty + jj][tx] = kv[(long)(s0 + ty + jj) * 4096 + h * 256 + 128 + d0 + tx];
        __syncthreads();
        const int txp = ((tx >> 2) & 3) * 8 + (tx >> 4) * 4 + (tx & 3);
        #pragma unroll
        for (int jj = 0; jj < 32; jj += 8)
            vt[(long)(h * 128 + d0 + ty + jj) * S_LEN + s0 + txp] = tile[tx][ty + jj];
    }
}

// ---------------------------------------------------------------------------
extern "C" void kernel_launch(void* const* d_in, const int* in_sizes, int n_in,
                              void* d_out, int out_size, void* d_ws, size_t ws_size,
                              hipStream_t stream)
{
    const float* x      = (const float*)d_in[0];
    const int*   posid  = (const int*)d_in[2];
    const float* cosb   = (const float*)d_in[3];
    const float* sinb   = (const float*)d_in[4];
    const float* q_a_w  = (const float*)d_in[5];
    const float* q_a_ln = (const float*)d_in[6];
    const float* q_b_w  = (const float*)d_in[7];
    const float* kv_a_w = (const float*)d_in[8];
    const float* kv_a_ln= (const float*)d_in[9];
    const float* kv_b_w = (const float*)d_in[10];
    const float* o_w    = (const float*)d_in[11];

    float* out    = (float*)d_out;
    float* kv_out = out + (size_t)2048 * 2048;

    char* ws = (char*)d_ws;
    size_t off = 0;
    auto alloc = [&](size_t bytes) { char* p = ws + off; off += (bytes + 255) & ~(size_t)255; return p; };
    u16* xb    = (u16*)alloc(2048ULL * 2048 * 2);
    u16* W1    = (u16*)alloc(2176ULL * 2048 * 2);   // [q_a^T ; kv_a^T(pad 640)]
    u16* qbwt  = (u16*)alloc(3072ULL * 1536 * 2);
    u16* kvbwt = (u16*)alloc(4096ULL * 512 * 2);
    u16* owt   = (u16*)alloc(2048ULL * 2048 * 2);
    u16* qkv_a = (u16*)alloc(2048ULL * 2176 * 2);   // [q_a(1536) | ckv(640)]
    u16* qbuf  = (u16*)alloc(2048ULL * 3072 * 2);
    u16* query = (u16*)alloc(16ULL * 2048 * 192 * 2);
    u16* cnb   = (u16*)alloc(2048ULL * 512 * 2);
    u16* kpe   = (u16*)alloc(2048ULL * 64 * 2);
    u16* kvbuf = (u16*)alloc(2048ULL * 4096 * 2);
    u16* vt    = (u16*)alloc(16ULL * 128 * 2048 * 2);
    u16* ao    = (u16*)alloc(2048ULL * 2048 * 2);
    (void)ws_size; (void)in_sizes; (void)n_in; (void)out_size;

    dim3 blk(256);

    // 0) fused conversions / weight transposes (19200 blocks)
    prep_k<<<dim3(19200), blk, 0, stream>>>(
        (const float4*)x, (ushort4*)xb, q_a_w, kv_a_w, q_b_w, kv_b_w, o_w,
        W1, qbwt, kvbwt, owt);

    // 1) [q_a | ckv] = x @ [q_a_w | kv_a_w]  (merged, N=2176)
    gemm_bt<0><<<dim3(17, 16), blk, 0, stream>>>(xb, W1, qkv_a, 2048, 2048, 2048, 2176);

    // 2) fused rmsnorm + kv norm/rope/cache
    norm_k<<<dim3(2048), blk, 0, stream>>>(qkv_a, q_a_ln, kv_a_ln, posid,
                                           cosb, sinb, kv_out, cnb, kpe);

    // 3) q = q_a_norm @ q_b_w  AND  kv = c_norm @ kv_b_w  (one dispatch)
    gemm_bt_dual<<<dim3(32, 16, 2), blk, 0, stream>>>(
        qkv_a, qbwt, qbuf, 1536, 2176, 1536, 3072, 24,
        cnb, kvbwt, kvbuf, 512, 512, 512, 4096, 32);

    // 4) fused qrope + value transpose
    post_k<<<dim3(6144), blk, 0, stream>>>(qbuf, posid, cosb, sinb, query, kvbuf, vt);

    // 5) fused flash attention (2-wave, pipelined) -> ao bf16 [S][H*128]
    flash_attn<<<dim3(512), dim3(128), 0, stream>>>(query, kvbuf, kpe, vt, ao);

    // 6) out = ao @ o_w (fp32)
    gemm_bt<1><<<dim3(16, 16), blk, 0, stream>>>(ao, owt, out, 2048, 2048, 2048, 2048);
}

// Round 9
// 395.298 us; speedup vs baseline: 1.0819x; 1.0819x over previous
//
#include <hip/hip_runtime.h>

typedef unsigned short u16;
typedef __bf16 bf16x8 __attribute__((ext_vector_type(8)));
typedef short s16x4 __attribute__((ext_vector_type(4)));
typedef short s16x8 __attribute__((ext_vector_type(8)));
typedef float f32x4 __attribute__((ext_vector_type(4)));

#define S_LEN 2048
#define NHEAD 16
#define QHEAD 192
#define EPS 1e-6f
#define ATTN_SCALE 0.07216878364870323f   /* 192^-0.5 */
#define QSCALE_LOG2E 0.10412011228586118f /* ATTN_SCALE * log2(e) */

__device__ __forceinline__ u16 f2bf(float f) {
    unsigned u = __builtin_bit_cast(unsigned, f);
    u = (u + 0x7FFFu + ((u >> 16) & 1u)) >> 16;
    return (u16)u;
}
__device__ __forceinline__ float bf2f(u16 h) {
    unsigned u = ((unsigned)h) << 16;
    return __builtin_bit_cast(float, u);
}

__device__ __forceinline__ void gl_lds16(const u16* g, u16* l) {
    __builtin_amdgcn_global_load_lds(
        (const __attribute__((address_space(1))) unsigned int*)g,
        (__attribute__((address_space(3))) unsigned int*)l,
        16, 0, 0);
}

#if defined(__has_builtin) && __has_builtin(__builtin_amdgcn_mfma_f32_16x16x16bf16_1k)
__device__ __forceinline__ f32x4 mfma16(s16x4 a, s16x4 b, f32x4 c) {
    return __builtin_amdgcn_mfma_f32_16x16x16bf16_1k(a, b, c, 0, 0, 0);
}
#else
__device__ __forceinline__ f32x4 mfma16(s16x4 a, s16x4 b, f32x4 c) {
    asm volatile("v_mfma_f32_16x16x16_bf16 %0, %1, %2, %0"
                 : "+v"(c) : "v"(a), "v"(b));
    return c;
}
#endif

// ---------------------------------------------------------------------------
// bf16 GEMM core:  C[M][N] = A[M][K] @ Bt[N][K]^T
// 4-wave (256-thread) blocks, 128x128 tile, wave-tile 64x64, BK=64 per
// iteration (two 32-chunks). Round-8 post-mortem arithmetic: per block-iter
// 1625 cyc measured vs ~385 LDS + ~80 MFMA -> ~1100 cyc of per-iteration
// barrier/latency chain. BK=64 halves barriers per K-element, and the
// prefetch (issued at iter top) gets a ~2x longer iteration to land before
// the single end-of-iter vmcnt(0)+s_barrier, so the drain is cheap.
// LDS 2 x 32KB = 64KB -> 2 blocks/CU. Buffer select by offset arithmetic
// (gfx950 addrspace-select miscompile with ternary LDS ptrs into gl_lds).
// sched_barrier(0) fences around waits per rule #18.
// ---------------------------------------------------------------------------
template <int CF32>
__device__ __forceinline__ void gemm_core(
    u16* __restrict__ smem,
    const u16* __restrict__ A, const u16* __restrict__ B, void* __restrict__ Cv,
    int K, int lda, int ldb, int ldc, int tm, int tn)
{
    const int tid = threadIdx.x;
    const int w = tid >> 6, lane = tid & 63;
    const int q = lane >> 4, r = lane & 15;

    const int lr = lane & 15;
    const int lc = (lane >> 4) * 8;
    // wave w stages A rows [w*32,+32) and B rows [w*32,+32), 2 k-chunks each
    const u16* ga0 = A + (long)(tm * 128 + w * 32 + lr) * lda + lc;
    const u16* ga1 = ga0 + 16 * (long)lda;
    const u16* gb0 = B + (long)(tn * 128 + w * 32 + lr) * ldb + lc;
    const u16* gb1 = gb0 + 16 * (long)ldb;
    const int sa0 = w * 1024, sa1 = sa0 + 512;
    const int sb0 = 4096 + w * 1024, sb1 = sb0 + 512;
    // buffer = 16384 u16 (32KB): sub-buf kk at +kk*8192 (A [0,4096), B [4096,8192))

    f32x4 acc[4][4] = {};
    const int wm = w >> 1;      // 64-row half
    const int wn = w & 1;       // 64-col half
    const int n = K >> 6;       // BK=64 iterations (K % 64 == 0 for all uses)

    // prologue: stage iter 0 (8 loads/wave)
    gl_lds16(ga0, smem + sa0);
    gl_lds16(ga1, smem + sa1);
    gl_lds16(gb0, smem + sb0);
    gl_lds16(gb1, smem + sb1);
    gl_lds16(ga0 + 32, smem + 8192 + sa0);
    gl_lds16(ga1 + 32, smem + 8192 + sa1);
    gl_lds16(gb0 + 32, smem + 8192 + sb0);
    gl_lds16(gb1 + 32, smem + 8192 + sb1);
    asm volatile("s_waitcnt vmcnt(0)" ::: "memory");
    __builtin_amdgcn_sched_barrier(0);
    __builtin_amdgcn_s_barrier();
    __builtin_amdgcn_sched_barrier(0);

    for (int t = 0; t < n; ++t) {
        u16* const cur = smem + (t & 1) * 16384;
        u16* const nxt = smem + ((t + 1) & 1) * 16384;
        if (t + 1 < n) {        // prefetch next BK=64 tile (full iter to land)
            const long k1 = (long)(t + 1) << 6;
            gl_lds16(ga0 + k1, nxt + sa0);
            gl_lds16(ga1 + k1, nxt + sa1);
            gl_lds16(gb0 + k1, nxt + sb0);
            gl_lds16(gb1 + k1, nxt + sb1);
            gl_lds16(ga0 + k1 + 32, nxt + 8192 + sa0);
            gl_lds16(ga1 + k1 + 32, nxt + 8192 + sa1);
            gl_lds16(gb0 + k1 + 32, nxt + 8192 + sb0);
            gl_lds16(gb1 + k1 + 32, nxt + 8192 + sb1);
        }
        #pragma unroll
        for (int kk = 0; kk < 2; ++kk) {
            u16* const sub = cur + kk * 8192;
            bf16x8 af[4], bv[4];
            #pragma unroll
            for (int mt = 0; mt < 4; ++mt)
                af[mt] = *(const bf16x8*)&sub[(wm * 4 + mt) * 512 + lane * 8];
            #pragma unroll
            for (int nt = 0; nt < 4; ++nt)
                bv[nt] = *(const bf16x8*)&sub[4096 + (wn * 4 + nt) * 512 + lane * 8];
            #pragma unroll
            for (int mt = 0; mt < 4; ++mt)
                #pragma unroll
                for (int nt = 0; nt < 4; ++nt)
                    acc[mt][nt] = __builtin_amdgcn_mfma_f32_16x16x32_bf16(
                        af[mt], bv[nt], acc[mt][nt], 0, 0, 0);
        }
        if (t + 1 < n) {
            asm volatile("s_waitcnt vmcnt(0)" ::: "memory");
            __builtin_amdgcn_sched_barrier(0);
            __builtin_amdgcn_s_barrier();
            __builtin_amdgcn_sched_barrier(0);
        }
    }

    const int row0 = tm * 128 + wm * 64 + q * 4;
    const int col0 = tn * 128 + wn * 64 + r;
    if (CF32) {
        float* C = (float*)Cv;
        #pragma unroll
        for (int mt = 0; mt < 4; ++mt)
            #pragma unroll
            for (int i = 0; i < 4; ++i) {
                long rb = (long)(row0 + mt * 16 + i) * ldc + col0;
                #pragma unroll
                for (int nt = 0; nt < 4; ++nt)
                    C[rb + nt * 16] = acc[mt][nt][i];
            }
    } else {
        u16* C = (u16*)Cv;
        #pragma unroll
        for (int mt = 0; mt < 4; ++mt)
            #pragma unroll
            for (int i = 0; i < 4; ++i) {
                long rb = (long)(row0 + mt * 16 + i) * ldc + col0;
                #pragma unroll
                for (int nt = 0; nt < 4; ++nt)
                    C[rb + nt * 16] = f2bf(acc[mt][nt][i]);
            }
    }
}

template <int CF32>
__global__ __launch_bounds__(256, 2)
void gemm_bt(const u16* __restrict__ A, const u16* __restrict__ B,
             void* __restrict__ Cv, int K, int lda, int ldb, int ldc)
{
    __shared__ __align__(16) u16 smem[2 * 16384];
    gemm_core<CF32>(smem, A, B, Cv, K, lda, ldb, ldc, blockIdx.y, blockIdx.x);
}

// Two independent GEMMs in ONE dispatch (z selects). Early-exit blocks
// return before any barrier (block-uniform - no hang).
__global__ __launch_bounds__(256, 2)
void gemm_bt_dual(const u16* __restrict__ A0, const u16* __restrict__ B0,
                  void* __restrict__ C0, int K0, int lda0, int ldb0, int ldc0, int nx0,
                  const u16* __restrict__ A1, const u16* __restrict__ B1,
                  void* __restrict__ C1, int K1, int lda1, int ldb1, int ldc1, int nx1)
{
    __shared__ __align__(16) u16 smem[2 * 16384];
    if (blockIdx.z == 0) {
        if ((int)blockIdx.x >= nx0) return;
        gemm_core<0>(smem, A0, B0, C0, K0, lda0, ldb0, ldc0, blockIdx.y, blockIdx.x);
    } else {
        if ((int)blockIdx.x >= nx1) return;
        gemm_core<0>(smem, A1, B1, C1, K1, lda1, ldb1, ldc1, blockIdx.y, blockIdx.x);
    }
}

// ---------------------------------------------------------------------------
// Flash attention, S^T formulation, double-buffered prefetch pipeline.
// REVERTED to the round-5/7 known-good config (66us): 4 waves x 16 q-rows,
// 256 threads, kv-tile 64, 2x40KB LDS (2 blocks/CU -> 8 waves/CU).
// Round-8's 2-wave variant halved LDS traffic but also halved occupancy
// (13%->6.3%) and doubled per-wave staging -> 112us. Flash is LATENCY-bound;
// occupancy is its currency, LDS throughput is not.
// PV reads are conflict-free ds_read_b128 via the s-permuted vt layout.
// Maxless exp2-domain softmax (query pre-scaled by SCALE*log2e).
// Grid: 1D 512, complementary pairing (b, b+256 share a CU).
// ---------------------------------------------------------------------------
template<int C0, int C1>
__device__ __forceinline__ void stage_tile(
    const u16* __restrict__ kvb, const u16* __restrict__ kpe,
    const u16* __restrict__ vt,
    u16* __restrict__ Kl, u16* __restrict__ Vl,
    int h, int t, int quad, int r)
{
    #pragma unroll
    for (int c = C0; c < C1; ++c) {
        if (c < 24) {
            const int mtk = c / 6, kc = c % 6;
            const int row = t * 64 + mtk * 16 + r;
            const u16* src = (kc < 4)
                ? kvb + (size_t)row * 4096 + h * 256 + kc * 32 + quad * 8
                : kpe + (size_t)row * 64 + (kc - 4) * 32 + quad * 8;
            gl_lds16(src, &Kl[c * 512]);
        } else {
            const int cv = c - 24, mtd = cv >> 1, sc = cv & 1;
            const u16* src = vt + ((size_t)h * 128 + mtd * 16 + r) * 2048
                             + t * 64 + sc * 32 + quad * 8;
            gl_lds16(src, &Vl[cv * 512]);
        }
    }
}

__device__ __forceinline__ void stage_dispatch(
    const u16* __restrict__ kvb, const u16* __restrict__ kpe,
    const u16* __restrict__ vt,
    u16* __restrict__ Kl, u16* __restrict__ Vl,
    int w, int h, int t, int quad, int r)
{
    if (w == 0)      stage_tile<0, 10>(kvb, kpe, vt, Kl, Vl, h, t, quad, r);
    else if (w == 1) stage_tile<10, 20>(kvb, kpe, vt, Kl, Vl, h, t, quad, r);
    else if (w == 2) stage_tile<20, 30>(kvb, kpe, vt, Kl, Vl, h, t, quad, r);
    else             stage_tile<30, 40>(kvb, kpe, vt, Kl, Vl, h, t, quad, r);
}

__device__ __forceinline__ void kv_tile_step(
    const u16* __restrict__ Kl, const u16* __restrict__ Vl,
    const bf16x8 (&Qf)[6], f32x4 (&Oacc)[8], float& lsum,
    int lane, int quad, int r, int kglob0, int qg, bool maskT)
{
    f32x4 Sacc[4];
    #pragma unroll
    for (int mtk = 0; mtk < 4; ++mtk)
        Sacc[mtk] = (f32x4){0.f, 0.f, 0.f, 0.f};
    #pragma unroll
    for (int kc = 0; kc < 6; ++kc)
        #pragma unroll
        for (int mtk = 0; mtk < 4; ++mtk) {
            bf16x8 Ak = *(const bf16x8*)&Kl[(mtk * 6 + kc) * 512 + lane * 8];
            Sacc[mtk] = __builtin_amdgcn_mfma_f32_16x16x32_bf16(
                Ak, Qf[kc], Sacc[mtk], 0, 0, 0);
        }
    #pragma unroll
    for (int sc = 0; sc < 2; ++sc) {
        s16x4 Pf[2];
        #pragma unroll
        for (int half = 0; half < 2; ++half) {
            const int kb = sc * 2 + half;
            const int kb0 = kglob0 + kb * 16 + quad * 4;
            #pragma unroll
            for (int i = 0; i < 4; ++i) {
                float pv = exp2f(Sacc[kb][i]);
                if (maskT && (kb0 + i > qg)) pv = 0.f;
                lsum += pv;
                Pf[half][i] = (short)f2bf(pv);
            }
        }
        #pragma unroll
        for (int mtd = 0; mtd < 8; ++mtd) {
            s16x8 Av8 = *(const s16x8*)&Vl[(mtd * 2 + sc) * 512 + quad * 128 + r * 8];
            s16x4 lo = __builtin_shufflevector(Av8, Av8, 0, 1, 2, 3);
            s16x4 hi = __builtin_shufflevector(Av8, Av8, 4, 5, 6, 7);
            Oacc[mtd] = mfma16(lo, Pf[0], Oacc[mtd]);
            Oacc[mtd] = mfma16(hi, Pf[1], Oacc[mtd]);
        }
    }
}

__global__ __launch_bounds__(256, 2)
void flash_attn(const u16* __restrict__ query, const u16* __restrict__ kvb,
                const u16* __restrict__ kpe, const u16* __restrict__ vt,
                u16* __restrict__ ao)
{
    const int tid = threadIdx.x;
    const int w = tid >> 6, lane = tid & 63;
    const int quad = lane >> 4, r = lane & 15;

    const int bid = (int)blockIdx.x;
    const int i = bid & 255;
    const int t_ = i >> 4;
    const int h = i & 15;
    const int j = (bid < 256) ? (31 - t_) : t_;

    const int q0 = j * 64;
    const int ntk = j + 1;

    __shared__ __align__(16) u16 smem[40960];   // 80KB: two 40KB tile buffers
    // buffer b at smem + b*20480: K = [0,12288) u16, V = [12288,20480) u16

    const int qg = q0 + w * 16 + r;   // this wave's q row (causal bound)

    bf16x8 Qf[6];
    #pragma unroll
    for (int kc = 0; kc < 6; ++kc)
        Qf[kc] = *(const bf16x8*)(query
            + ((size_t)h * S_LEN + q0 + w * 16 + r) * QHEAD
            + kc * 32 + quad * 8);

    f32x4 Oacc[8];
    #pragma unroll
    for (int mtd = 0; mtd < 8; ++mtd)
        Oacc[mtd] = (f32x4){0.f, 0.f, 0.f, 0.f};
    float lsum = 0.f;

    // prologue: stage tile 0 into buffer 0
    stage_dispatch(kvb, kpe, vt, smem, smem + 12288, w, h, 0, quad, r);
    __syncthreads();

    for (int t = 0; t < ntk; ++t) {
        u16* const curb = smem + (t & 1) * 20480;          // offset arith,
        u16* const nxtb = smem + ((t + 1) & 1) * 20480;    // no ptr select
        if (t + 1 < ntk)
            stage_dispatch(kvb, kpe, vt, nxtb, nxtb + 12288, w, h, t + 1, quad, r);
        kv_tile_step(curb, curb + 12288, Qf, Oacc, lsum,
                     lane, quad, r, t * 64, qg, t == ntk - 1);
        __syncthreads();
    }

    // epilogue: each wave owns its 16 q-rows; reduce lsum over quads only
    float l = lsum;
    l += __shfl_xor(l, 16, 64);
    l += __shfl_xor(l, 32, 64);
    const float inv = 1.0f / l;
    const int qrow = q0 + w * 16 + r;
    #pragma unroll
    for (int mtd = 0; mtd < 8; ++mtd) {
        ushort4 o;
        o.x = f2bf(Oacc[mtd][0] * inv);
        o.y = f2bf(Oacc[mtd][1] * inv);
        o.z = f2bf(Oacc[mtd][2] * inv);
        o.w = f2bf(Oacc[mtd][3] * inv);
        *(ushort4*)(ao + (size_t)qrow * 2048 + h * 128 + mtd * 16 + quad * 4) = o;
    }
}

// ---------------------------------------------------------------------------
// prep_k: fused input-convert + 5 weight transposes (was 6 dispatches).
// Flattened 1D grid of 19200 blocks x 256 threads; branches block-uniform.
// ---------------------------------------------------------------------------
__device__ __forceinline__ void wtrans_body(
    float (*tile)[33], const float* __restrict__ in, u16* __restrict__ out,
    int K, int N, int bx, int by, int tid)
{
    const int tx = tid & 31, ty = tid >> 5;   // 32 x 8
    const int k0 = bx * 32, n0 = by * 32;
    #pragma unroll
    for (int jj = 0; jj < 32; jj += 8) {
        int nn = n0 + tx;
        tile[ty + jj][tx] = (nn < N) ? in[(long)(k0 + ty + jj) * N + nn] : 0.0f;
    }
    __syncthreads();
    #pragma unroll
    for (int jj = 0; jj < 32; jj += 8)
        out[(long)(n0 + ty + jj) * K + k0 + tx] = f2bf(tile[tx][ty + jj]);
}

__global__ __launch_bounds__(256)
void prep_k(const float4* __restrict__ x4, ushort4* __restrict__ xb4,
            const float* __restrict__ q_a_w, const float* __restrict__ kv_a_w,
            const float* __restrict__ q_b_w, const float* __restrict__ kv_b_w,
            const float* __restrict__ o_w,
            u16* __restrict__ W1, u16* __restrict__ qbwt,
            u16* __restrict__ kvbwt, u16* __restrict__ owt)
{
    __shared__ float tile[32][33];
    const int tid = threadIdx.x;
    int b = (int)blockIdx.x;
    if (b < 4096) {
        int i = b * 256 + tid;     // exactly 1048576 float4s
        float4 v = x4[i];
        ushort4 o;
        o.x = f2bf(v.x); o.y = f2bf(v.y); o.z = f2bf(v.z); o.w = f2bf(v.w);
        xb4[i] = o;
        return;
    }
    b -= 4096;
    if (b < 3072)       wtrans_body(tile, q_a_w,  W1,                  2048, 1536, b % 64, b / 64, tid);
    else if ((b -= 3072) < 1280) wtrans_body(tile, kv_a_w, W1 + 1536ULL * 2048, 2048, 576,  b % 64, b / 64, tid);
    else if ((b -= 1280) < 4608) wtrans_body(tile, q_b_w,  qbwt,       1536, 3072, b % 48, b / 48, tid);
    else if ((b -= 4608) < 2048) wtrans_body(tile, kv_b_w, kvbwt,      512,  4096, b % 16, b / 16, tid);
    else { b -= 2048;            wtrans_body(tile, o_w,    owt,        2048, 2048, b % 64, b / 64, tid); }
}

// ---------------------------------------------------------------------------
// norm_k: fused q_a rmsnorm (1536 cols, in-place) + kv_a norm/rope/cache.
// ---------------------------------------------------------------------------
__global__ __launch_bounds__(256)
void norm_k(u16* __restrict__ qkv, const float* __restrict__ q_ln,
            const float* __restrict__ kv_ln, const int* __restrict__ pos_ids,
            const float* __restrict__ cosb, const float* __restrict__ sinb,
            float* __restrict__ kvout, u16* __restrict__ cnb,
            u16* __restrict__ kpe)
{
    const int s = blockIdx.x, tid = threadIdx.x;
    u16* row = qkv + (long)s * 2176;
    u16* row2 = row + 1536;
    __shared__ float red[8];
    float sum = 0.f;
    for (int d = tid; d < 1536; d += 256) { float v = bf2f(row[d]); sum += v * v; }
    #pragma unroll
    for (int o = 32; o; o >>= 1) sum += __shfl_xor(sum, o, 64);
    if ((tid & 63) == 0) red[tid >> 6] = sum;
    float sum2 = 0.f;
    for (int d = tid; d < 512; d += 256) { float v = bf2f(row2[d]); sum2 += v * v; }
    #pragma unroll
    for (int o = 32; o; o >>= 1) sum2 += __shfl_xor(sum2, o, 64);
    if ((tid & 63) == 0) red[4 + (tid >> 6)] = sum2;
    __syncthreads();
    sum  = red[0] + red[1] + red[2] + red[3];
    sum2 = red[4] + red[5] + red[6] + red[7];
    const float sc1 = rsqrtf(sum / 1536.f + EPS);
    const float sc2 = rsqrtf(sum2 / 512.f + EPS);
    for (int d = tid; d < 1536; d += 256)
        row[d] = f2bf(bf2f(row[d]) * sc1 * q_ln[d]);
    for (int d = tid; d < 512; d += 256) {
        float v = bf2f(row2[d]) * sc2 * kv_ln[d];
        kvout[(long)s * 576 + d] = v;
        cnb[(long)s * 512 + d] = f2bf(v);
    }
    if (tid < 32) {
        int p = pos_ids[s];
        float x0 = bf2f(row2[512 + 2 * tid]);
        float x1 = bf2f(row2[512 + 2 * tid + 1]);
        float c1 = cosb[p * 64 + tid], s1 = sinb[p * 64 + tid];
        float c2 = cosb[p * 64 + 32 + tid], s2 = sinb[p * 64 + 32 + tid];
        float lo = x0 * c1 - x1 * s1;
        float hi = x1 * c2 + x0 * s2;
        kvout[(long)s * 576 + 512 + tid] = lo;
        kvout[(long)s * 576 + 544 + tid] = hi;
        kpe[(long)s * 64 + tid] = f2bf(lo);
        kpe[(long)s * 64 + 32 + tid] = f2bf(hi);
    }
}

// ---------------------------------------------------------------------------
// post_k: fused qrope ([0,2048) blocks) + vtrans ([2048,6144) blocks).
// vtrans s-axis permuted within 32-blocks so flash PV reads b128:
// new position quad*8 + half*4 + i  <->  s = half*16 + quad*4 + i.
// ---------------------------------------------------------------------------
__global__ __launch_bounds__(256)
void post_k(const u16* __restrict__ qb, const int* __restrict__ pos_ids,
            const float* __restrict__ cosb, const float* __restrict__ sinb,
            u16* __restrict__ query, const u16* __restrict__ kv,
            u16* __restrict__ vt)
{
    __shared__ u16 tile[32][33];
    const int tid = threadIdx.x;
    int b = (int)blockIdx.x;
    if (b < 2048) {
        const int s = b;
        const u16* row = qb + (long)s * 3072;
        {   // nope part: 16 heads x 16 chunks of 8, scaled
            int h = tid >> 4, c = tid & 15;
            const u16* src = &row[h * QHEAD + c * 8];
            u16* dst = &query[((long)(h * S_LEN + s)) * QHEAD + c * 8];
            ushort4 a = *(const ushort4*)src;
            ushort4 bb = *(const ushort4*)(src + 4);
            ushort4 oa, ob;
            oa.x = f2bf(bf2f(a.x) * QSCALE_LOG2E); oa.y = f2bf(bf2f(a.y) * QSCALE_LOG2E);
            oa.z = f2bf(bf2f(a.z) * QSCALE_LOG2E); oa.w = f2bf(bf2f(a.w) * QSCALE_LOG2E);
            ob.x = f2bf(bf2f(bb.x) * QSCALE_LOG2E); ob.y = f2bf(bf2f(bb.y) * QSCALE_LOG2E);
            ob.z = f2bf(bf2f(bb.z) * QSCALE_LOG2E); ob.w = f2bf(bf2f(bb.w) * QSCALE_LOG2E);
            *(ushort4*)dst = oa;
            *(ushort4*)(dst + 4) = ob;
        }
        int p = pos_ids[s];
        for (int idx = tid; idx < 512; idx += 256) {
            int h = idx >> 5, i = idx & 31;
            float x0 = bf2f(row[h * QHEAD + 128 + 2 * i]);
            float x1 = bf2f(row[h * QHEAD + 128 + 2 * i + 1]);
            float c1 = cosb[p * 64 + i], s1 = sinb[p * 64 + i];
            float c2 = cosb[p * 64 + 32 + i], s2 = sinb[p * 64 + 32 + i];
            u16* qr = query + ((long)(h * S_LEN + s)) * QHEAD;
            qr[128 + i] = f2bf((x0 * c1 - x1 * s1) * QSCALE_LOG2E);
            qr[160 + i] = f2bf((x1 * c2 + x0 * s2) * QSCALE_LOG2E);
        }
    } else {
        b -= 2048;
        const int s0 = (b & 63) * 32, d0 = ((b >> 6) & 3) * 32, h = b >> 8;
        const int tx = tid & 31, ty = tid >> 5;
        #pragma unroll
        for (int jj = 0; jj < 32; jj += 8)
            tile[ty + jj][tx] = kv[(long)(s0 + ty + jj) * 4096 + h * 256 + 128 + d0 + tx];
        __syncthreads();
        const int txp = ((tx >> 2) & 3) * 8 + (tx >> 4) * 4 + (tx & 3);
        #pragma unroll
        for (int jj = 0; jj < 32; jj += 8)
            vt[(long)(h * 128 + d0 + ty + jj) * S_LEN + s0 + txp] = tile[tx][ty + jj];
    }
}

// ---------------------------------------------------------------------------
extern "C" void kernel_launch(void* const* d_in, const int* in_sizes, int n_in,
                              void* d_out, int out_size, void* d_ws, size_t ws_size,
                              hipStream_t stream)
{
    const float* x      = (const float*)d_in[0];
    const int*   posid  = (const int*)d_in[2];
    const float* cosb   = (const float*)d_in[3];
    const float* sinb   = (const float*)d_in[4];
    const float* q_a_w  = (const float*)d_in[5];
    const float* q_a_ln = (const float*)d_in[6];
    const float* q_b_w  = (const float*)d_in[7];
    const float* kv_a_w = (const float*)d_in[8];
    const float* kv_a_ln= (const float*)d_in[9];
    const float* kv_b_w = (const float*)d_in[10];
    const float* o_w    = (const float*)d_in[11];

    float* out    = (float*)d_out;
    float* kv_out = out + (size_t)2048 * 2048;

    char* ws = (char*)d_ws;
    size_t off = 0;
    auto alloc = [&](size_t bytes) { char* p = ws + off; off += (bytes + 255) & ~(size_t)255; return p; };
    u16* xb    = (u16*)alloc(2048ULL * 2048 * 2);
    u16* W1    = (u16*)alloc(2176ULL * 2048 * 2);   // [q_a^T ; kv_a^T(pad 640)]
    u16* qbwt  = (u16*)alloc(3072ULL * 1536 * 2);
    u16* kvbwt = (u16*)alloc(4096ULL * 512 * 2);
    u16* owt   = (u16*)alloc(2048ULL * 2048 * 2);
    u16* qkv_a = (u16*)alloc(2048ULL * 2176 * 2);   // [q_a(1536) | ckv(640)]
    u16* qbuf  = (u16*)alloc(2048ULL * 3072 * 2);
    u16* query = (u16*)alloc(16ULL * 2048 * 192 * 2);
    u16* cnb   = (u16*)alloc(2048ULL * 512 * 2);
    u16* kpe   = (u16*)alloc(2048ULL * 64 * 2);
    u16* kvbuf = (u16*)alloc(2048ULL * 4096 * 2);
    u16* vt    = (u16*)alloc(16ULL * 128 * 2048 * 2);
    u16* ao    = (u16*)alloc(2048ULL * 2048 * 2);
    (void)ws_size; (void)in_sizes; (void)n_in; (void)out_size;

    dim3 blk(256);

    // 0) fused conversions / weight transposes (19200 blocks)
    prep_k<<<dim3(19200), blk, 0, stream>>>(
        (const float4*)x, (ushort4*)xb, q_a_w, kv_a_w, q_b_w, kv_b_w, o_w,
        W1, qbwt, kvbwt, owt);

    // 1) [q_a | ckv] = x @ [q_a_w | kv_a_w]  (merged, N=2176)
    gemm_bt<0><<<dim3(17, 16), blk, 0, stream>>>(xb, W1, qkv_a, 2048, 2048, 2048, 2176);

    // 2) fused rmsnorm + kv norm/rope/cache
    norm_k<<<dim3(2048), blk, 0, stream>>>(qkv_a, q_a_ln, kv_a_ln, posid,
                                           cosb, sinb, kv_out, cnb, kpe);

    // 3) q = q_a_norm @ q_b_w  AND  kv = c_norm @ kv_b_w  (one dispatch)
    gemm_bt_dual<<<dim3(32, 16, 2), blk, 0, stream>>>(
        qkv_a, qbwt, qbuf, 1536, 2176, 1536, 3072, 24,
        cnb, kvbwt, kvbuf, 512, 512, 512, 4096, 32);

    // 4) fused qrope + value transpose
    post_k<<<dim3(6144), blk, 0, stream>>>(qbuf, posid, cosb, sinb, query, kvbuf, vt);

    // 5) fused flash attention (4-wave, pipelined) -> ao bf16 [S][H*128]
    flash_attn<<<dim3(512), dim3(256), 0, stream>>>(query, kvbuf, kpe, vt, ao);

    // 6) out = ao @ o_w (fp32)
    gemm_bt<1><<<dim3(16, 16), blk, 0, stream>>>(ao, owt, out, 2048, 2048, 2048, 2048);
}

// Round 10
// 395.256 us; speedup vs baseline: 1.0820x; 1.0001x over previous
//
#include <hip/hip_runtime.h>

typedef unsigned short u16;
typedef __bf16 bf16x8 __attribute__((ext_vector_type(8)));
typedef short s16x4 __attribute__((ext_vector_type(4)));
typedef short s16x8 __attribute__((ext_vector_type(8)));
typedef float f32x4 __attribute__((ext_vector_type(4)));

#define S_LEN 2048
#define NHEAD 16
#define QHEAD 192
#define EPS 1e-6f
#define ATTN_SCALE 0.07216878364870323f   /* 192^-0.5 */
#define QSCALE_LOG2E 0.10412011228586118f /* ATTN_SCALE * log2(e) */

__device__ __forceinline__ u16 f2bf(float f) {
    unsigned u = __builtin_bit_cast(unsigned, f);
    u = (u + 0x7FFFu + ((u >> 16) & 1u)) >> 16;
    return (u16)u;
}
__device__ __forceinline__ float bf2f(u16 h) {
    unsigned u = ((unsigned)h) << 16;
    return __builtin_bit_cast(float, u);
}

__device__ __forceinline__ void gl_lds16(const u16* g, u16* l) {
    __builtin_amdgcn_global_load_lds(
        (const __attribute__((address_space(1))) unsigned int*)g,
        (__attribute__((address_space(3))) unsigned int*)l,
        16, 0, 0);
}

#if defined(__has_builtin) && __has_builtin(__builtin_amdgcn_mfma_f32_16x16x16bf16_1k)
__device__ __forceinline__ f32x4 mfma16(s16x4 a, s16x4 b, f32x4 c) {
    return __builtin_amdgcn_mfma_f32_16x16x16bf16_1k(a, b, c, 0, 0, 0);
}
#else
__device__ __forceinline__ f32x4 mfma16(s16x4 a, s16x4 b, f32x4 c) {
    asm volatile("v_mfma_f32_16x16x16_bf16 %0, %1, %2, %0"
                 : "+v"(c) : "v"(a), "v"(b));
    return c;
}
#endif

// XCD-pinning swizzle: for launch grids where XCD = blockIdx.x & 7
// (true when gridDim.x or the z-offset is 0 mod 8), map x -> a tile
// coordinate so XCD k owns a CONTIGUOUS slab of `chunk` tiles:
// coord = (x&7)*chunk + (x>>3). Bijective for x < 8*chunk. Makes the
// re-read operand panels (0.5-1.6MB per XCD) L2-resident instead of
// streaming from L3 on every re-read (round-9 post-mortem: GEMMs are
// L3-BW-bound; panel re-read traffic ~436MB/dispatch vs 4MB L2/XCD).
__device__ __forceinline__ int swz8(int x, int chunk) {
    return (x & 7) * chunk + (x >> 3);
}

// ---------------------------------------------------------------------------
// bf16 GEMM core:  C[M][N] = A[M][K] @ Bt[N][K]^T
// 4-wave (256-thread) blocks, 128x128 tile, wave-tile 64x64, BK=64 per
// iteration, double-buffered prefetch with end-of-iter vmcnt(0)+s_barrier.
// LDS 2 x 32KB = 64KB -> 2 blocks/CU. Buffer select by offset arithmetic
// (gfx950 addrspace-select miscompile with ternary LDS ptrs into gl_lds).
// sched_barrier(0) fences around waits per rule #18.
// ---------------------------------------------------------------------------
template <int CF32>
__device__ __forceinline__ void gemm_core(
    u16* __restrict__ smem,
    const u16* __restrict__ A, const u16* __restrict__ B, void* __restrict__ Cv,
    int K, int lda, int ldb, int ldc, int tm, int tn)
{
    const int tid = threadIdx.x;
    const int w = tid >> 6, lane = tid & 63;
    const int q = lane >> 4, r = lane & 15;

    const int lr = lane & 15;
    const int lc = (lane >> 4) * 8;
    // wave w stages A rows [w*32,+32) and B rows [w*32,+32), 2 k-chunks each
    const u16* ga0 = A + (long)(tm * 128 + w * 32 + lr) * lda + lc;
    const u16* ga1 = ga0 + 16 * (long)lda;
    const u16* gb0 = B + (long)(tn * 128 + w * 32 + lr) * ldb + lc;
    const u16* gb1 = gb0 + 16 * (long)ldb;
    const int sa0 = w * 1024, sa1 = sa0 + 512;
    const int sb0 = 4096 + w * 1024, sb1 = sb0 + 512;
    // buffer = 16384 u16 (32KB): sub-buf kk at +kk*8192 (A [0,4096), B [4096,8192))

    f32x4 acc[4][4] = {};
    const int wm = w >> 1;      // 64-row half
    const int wn = w & 1;       // 64-col half
    const int n = K >> 6;       // BK=64 iterations (K % 64 == 0 for all uses)

    // prologue: stage iter 0 (8 loads/wave)
    gl_lds16(ga0, smem + sa0);
    gl_lds16(ga1, smem + sa1);
    gl_lds16(gb0, smem + sb0);
    gl_lds16(gb1, smem + sb1);
    gl_lds16(ga0 + 32, smem + 8192 + sa0);
    gl_lds16(ga1 + 32, smem + 8192 + sa1);
    gl_lds16(gb0 + 32, smem + 8192 + sb0);
    gl_lds16(gb1 + 32, smem + 8192 + sb1);
    asm volatile("s_waitcnt vmcnt(0)" ::: "memory");
    __builtin_amdgcn_sched_barrier(0);
    __builtin_amdgcn_s_barrier();
    __builtin_amdgcn_sched_barrier(0);

    for (int t = 0; t < n; ++t) {
        u16* const cur = smem + (t & 1) * 16384;
        u16* const nxt = smem + ((t + 1) & 1) * 16384;
        if (t + 1 < n) {        // prefetch next BK=64 tile (full iter to land)
            const long k1 = (long)(t + 1) << 6;
            gl_lds16(ga0 + k1, nxt + sa0);
            gl_lds16(ga1 + k1, nxt + sa1);
            gl_lds16(gb0 + k1, nxt + sb0);
            gl_lds16(gb1 + k1, nxt + sb1);
            gl_lds16(ga0 + k1 + 32, nxt + 8192 + sa0);
            gl_lds16(ga1 + k1 + 32, nxt + 8192 + sa1);
            gl_lds16(gb0 + k1 + 32, nxt + 8192 + sb0);
            gl_lds16(gb1 + k1 + 32, nxt + 8192 + sb1);
        }
        #pragma unroll
        for (int kk = 0; kk < 2; ++kk) {
            u16* const sub = cur + kk * 8192;
            bf16x8 af[4], bv[4];
            #pragma unroll
            for (int mt = 0; mt < 4; ++mt)
                af[mt] = *(const bf16x8*)&sub[(wm * 4 + mt) * 512 + lane * 8];
            #pragma unroll
            for (int nt = 0; nt < 4; ++nt)
                bv[nt] = *(const bf16x8*)&sub[4096 + (wn * 4 + nt) * 512 + lane * 8];
            #pragma unroll
            for (int mt = 0; mt < 4; ++mt)
                #pragma unroll
                for (int nt = 0; nt < 4; ++nt)
                    acc[mt][nt] = __builtin_amdgcn_mfma_f32_16x16x32_bf16(
                        af[mt], bv[nt], acc[mt][nt], 0, 0, 0);
        }
        if (t + 1 < n) {
            asm volatile("s_waitcnt vmcnt(0)" ::: "memory");
            __builtin_amdgcn_sched_barrier(0);
            __builtin_amdgcn_s_barrier();
            __builtin_amdgcn_sched_barrier(0);
        }
    }

    const int row0 = tm * 128 + wm * 64 + q * 4;
    const int col0 = tn * 128 + wn * 64 + r;
    if (CF32) {
        float* C = (float*)Cv;
        #pragma unroll
        for (int mt = 0; mt < 4; ++mt)
            #pragma unroll
            for (int i = 0; i < 4; ++i) {
                long rb = (long)(row0 + mt * 16 + i) * ldc + col0;
                #pragma unroll
                for (int nt = 0; nt < 4; ++nt)
                    C[rb + nt * 16] = acc[mt][nt][i];
            }
    } else {
        u16* C = (u16*)Cv;
        #pragma unroll
        for (int mt = 0; mt < 4; ++mt)
            #pragma unroll
            for (int i = 0; i < 4; ++i) {
                long rb = (long)(row0 + mt * 16 + i) * ldc + col0;
                #pragma unroll
                for (int nt = 0; nt < 4; ++nt)
                    C[rb + nt * 16] = f2bf(acc[mt][nt][i]);
            }
    }
}

// XISM=1: swizzled x-coord is the tile ROW (tm), y is tn.
// XISM=0: swizzled x-coord is the tile COL (tn), y is tm.
template <int CF32, int XISM>
__global__ __launch_bounds__(256, 2)
void gemm_bt(const u16* __restrict__ A, const u16* __restrict__ B,
             void* __restrict__ Cv, int K, int lda, int ldb, int ldc, int chunk)
{
    __shared__ __align__(16) u16 smem[2 * 16384];
    const int s = swz8((int)blockIdx.x, chunk);
    const int tm = XISM ? s : (int)blockIdx.y;
    const int tn = XISM ? (int)blockIdx.y : s;
    gemm_core<CF32>(smem, A, B, Cv, K, lda, ldb, ldc, tm, tn);
}

// Two independent GEMMs in ONE dispatch (z selects). Early-exit blocks
// return before any barrier (block-uniform - no hang). XCD = x&7 for both
// z-slices (z-offset 512 = 0 mod 8), so swz8 pins each XCD to a tn-slab.
__global__ __launch_bounds__(256, 2)
void gemm_bt_dual(const u16* __restrict__ A0, const u16* __restrict__ B0,
                  void* __restrict__ C0, int K0, int lda0, int ldb0, int ldc0, int nx0,
                  const u16* __restrict__ A1, const u16* __restrict__ B1,
                  void* __restrict__ C1, int K1, int lda1, int ldb1, int ldc1, int nx1)
{
    __shared__ __align__(16) u16 smem[2 * 16384];
    if (blockIdx.z == 0) {
        if ((int)blockIdx.x >= nx0) return;
        gemm_core<0>(smem, A0, B0, C0, K0, lda0, ldb0, ldc0,
                     blockIdx.y, swz8((int)blockIdx.x, nx0 >> 3));
    } else {
        if ((int)blockIdx.x >= nx1) return;
        gemm_core<0>(smem, A1, B1, C1, K1, lda1, ldb1, ldc1,
                     blockIdx.y, swz8((int)blockIdx.x, nx1 >> 3));
    }
}

// ---------------------------------------------------------------------------
// Flash attention, S^T formulation, double-buffered prefetch pipeline.
// Known-good round-5/7/9 config (66us): 4 waves x 16 q-rows, 256 threads,
// kv-tile 64, 2x40KB LDS (2 blocks/CU -> 8 waves/CU). Latency-bound;
// occupancy is its currency. PV reads conflict-free b128 via s-permuted vt.
// Maxless exp2-domain softmax. Grid 1D 512, complementary pairing.
// ---------------------------------------------------------------------------
template<int C0, int C1>
__device__ __forceinline__ void stage_tile(
    const u16* __restrict__ kvb, const u16* __restrict__ kpe,
    const u16* __restrict__ vt,
    u16* __restrict__ Kl, u16* __restrict__ Vl,
    int h, int t, int quad, int r)
{
    #pragma unroll
    for (int c = C0; c < C1; ++c) {
        if (c < 24) {
            const int mtk = c / 6, kc = c % 6;
            const int row = t * 64 + mtk * 16 + r;
            const u16* src = (kc < 4)
                ? kvb + (size_t)row * 4096 + h * 256 + kc * 32 + quad * 8
                : kpe + (size_t)row * 64 + (kc - 4) * 32 + quad * 8;
            gl_lds16(src, &Kl[c * 512]);
        } else {
            const int cv = c - 24, mtd = cv >> 1, sc = cv & 1;
            const u16* src = vt + ((size_t)h * 128 + mtd * 16 + r) * 2048
                             + t * 64 + sc * 32 + quad * 8;
            gl_lds16(src, &Vl[cv * 512]);
        }
    }
}

__device__ __forceinline__ void stage_dispatch(
    const u16* __restrict__ kvb, const u16* __restrict__ kpe,
    const u16* __restrict__ vt,
    u16* __restrict__ Kl, u16* __restrict__ Vl,
    int w, int h, int t, int quad, int r)
{
    if (w == 0)      stage_tile<0, 10>(kvb, kpe, vt, Kl, Vl, h, t, quad, r);
    else if (w == 1) stage_tile<10, 20>(kvb, kpe, vt, Kl, Vl, h, t, quad, r);
    else if (w == 2) stage_tile<20, 30>(kvb, kpe, vt, Kl, Vl, h, t, quad, r);
    else             stage_tile<30, 40>(kvb, kpe, vt, Kl, Vl, h, t, quad, r);
}

__device__ __forceinline__ void kv_tile_step(
    const u16* __restrict__ Kl, const u16* __restrict__ Vl,
    const bf16x8 (&Qf)[6], f32x4 (&Oacc)[8], float& lsum,
    int lane, int quad, int r, int kglob0, int qg, bool maskT)
{
    f32x4 Sacc[4];
    #pragma unroll
    for (int mtk = 0; mtk < 4; ++mtk)
        Sacc[mtk] = (f32x4){0.f, 0.f, 0.f, 0.f};
    #pragma unroll
    for (int kc = 0; kc < 6; ++kc)
        #pragma unroll
        for (int mtk = 0; mtk < 4; ++mtk) {
            bf16x8 Ak = *(const bf16x8*)&Kl[(mtk * 6 + kc) * 512 + lane * 8];
            Sacc[mtk] = __builtin_amdgcn_mfma_f32_16x16x32_bf16(
                Ak, Qf[kc], Sacc[mtk], 0, 0, 0);
        }
    #pragma unroll
    for (int sc = 0; sc < 2; ++sc) {
        s16x4 Pf[2];
        #pragma unroll
        for (int half = 0; half < 2; ++half) {
            const int kb = sc * 2 + half;
            const int kb0 = kglob0 + kb * 16 + quad * 4;
            #pragma unroll
            for (int i = 0; i < 4; ++i) {
                float pv = exp2f(Sacc[kb][i]);
                if (maskT && (kb0 + i > qg)) pv = 0.f;
                lsum += pv;
                Pf[half][i] = (short)f2bf(pv);
            }
        }
        #pragma unroll
        for (int mtd = 0; mtd < 8; ++mtd) {
            s16x8 Av8 = *(const s16x8*)&Vl[(mtd * 2 + sc) * 512 + quad * 128 + r * 8];
            s16x4 lo = __builtin_shufflevector(Av8, Av8, 0, 1, 2, 3);
            s16x4 hi = __builtin_shufflevector(Av8, Av8, 4, 5, 6, 7);
            Oacc[mtd] = mfma16(lo, Pf[0], Oacc[mtd]);
            Oacc[mtd] = mfma16(hi, Pf[1], Oacc[mtd]);
        }
    }
}

__global__ __launch_bounds__(256, 2)
void flash_attn(const u16* __restrict__ query, const u16* __restrict__ kvb,
                const u16* __restrict__ kpe, const u16* __restrict__ vt,
                u16* __restrict__ ao)
{
    const int tid = threadIdx.x;
    const int w = tid >> 6, lane = tid & 63;
    const int quad = lane >> 4, r = lane & 15;

    const int bid = (int)blockIdx.x;
    const int i = bid & 255;
    const int t_ = i >> 4;
    const int h = i & 15;
    const int j = (bid < 256) ? (31 - t_) : t_;

    const int q0 = j * 64;
    const int ntk = j + 1;

    __shared__ __align__(16) u16 smem[40960];   // 80KB: two 40KB tile buffers
    // buffer b at smem + b*20480: K = [0,12288) u16, V = [12288,20480) u16

    const int qg = q0 + w * 16 + r;   // this wave's q row (causal bound)

    bf16x8 Qf[6];
    #pragma unroll
    for (int kc = 0; kc < 6; ++kc)
        Qf[kc] = *(const bf16x8*)(query
            + ((size_t)h * S_LEN + q0 + w * 16 + r) * QHEAD
            + kc * 32 + quad * 8);

    f32x4 Oacc[8];
    #pragma unroll
    for (int mtd = 0; mtd < 8; ++mtd)
        Oacc[mtd] = (f32x4){0.f, 0.f, 0.f, 0.f};
    float lsum = 0.f;

    // prologue: stage tile 0 into buffer 0
    stage_dispatch(kvb, kpe, vt, smem, smem + 12288, w, h, 0, quad, r);
    __syncthreads();

    for (int t = 0; t < ntk; ++t) {
        u16* const curb = smem + (t & 1) * 20480;          // offset arith,
        u16* const nxtb = smem + ((t + 1) & 1) * 20480;    // no ptr select
        if (t + 1 < ntk)
            stage_dispatch(kvb, kpe, vt, nxtb, nxtb + 12288, w, h, t + 1, quad, r);
        kv_tile_step(curb, curb + 12288, Qf, Oacc, lsum,
                     lane, quad, r, t * 64, qg, t == ntk - 1);
        __syncthreads();
    }

    // epilogue: each wave owns its 16 q-rows; reduce lsum over quads only
    float l = lsum;
    l += __shfl_xor(l, 16, 64);
    l += __shfl_xor(l, 32, 64);
    const float inv = 1.0f / l;
    const int qrow = q0 + w * 16 + r;
    #pragma unroll
    for (int mtd = 0; mtd < 8; ++mtd) {
        ushort4 o;
        o.x = f2bf(Oacc[mtd][0] * inv);
        o.y = f2bf(Oacc[mtd][1] * inv);
        o.z = f2bf(Oacc[mtd][2] * inv);
        o.w = f2bf(Oacc[mtd][3] * inv);
        *(ushort4*)(ao + (size_t)qrow * 2048 + h * 128 + mtd * 16 + quad * 4) = o;
    }
}

// ---------------------------------------------------------------------------
// prep_k: fused input-convert + 5 weight transposes (was 6 dispatches).
// Flattened 1D grid of 19200 blocks x 256 threads; branches block-uniform.
// ---------------------------------------------------------------------------
__device__ __forceinline__ void wtrans_body(
    float (*tile)[33], const float* __restrict__ in, u16* __restrict__ out,
    int K, int N, int bx, int by, int tid)
{
    const int tx = tid & 31, ty = tid >> 5;   // 32 x 8
    const int k0 = bx * 32, n0 = by * 32;
    #pragma unroll
    for (int jj = 0; jj < 32; jj += 8) {
        int nn = n0 + tx;
        tile[ty + jj][tx] = (nn < N) ? in[(long)(k0 + ty + jj) * N + nn] : 0.0f;
    }
    __syncthreads();
    #pragma unroll
    for (int jj = 0; jj < 32; jj += 8)
        out[(long)(n0 + ty + jj) * K + k0 + tx] = f2bf(tile[tx][ty + jj]);
}

__global__ __launch_bounds__(256)
void prep_k(const float4* __restrict__ x4, ushort4* __restrict__ xb4,
            const float* __restrict__ q_a_w, const float* __restrict__ kv_a_w,
            const float* __restrict__ q_b_w, const float* __restrict__ kv_b_w,
            const float* __restrict__ o_w,
            u16* __restrict__ W1, u16* __restrict__ qbwt,
            u16* __restrict__ kvbwt, u16* __restrict__ owt)
{
    __shared__ float tile[32][33];
    const int tid = threadIdx.x;
    int b = (int)blockIdx.x;
    if (b < 4096) {
        int i = b * 256 + tid;     // exactly 1048576 float4s
        float4 v = x4[i];
        ushort4 o;
        o.x = f2bf(v.x); o.y = f2bf(v.y); o.z = f2bf(v.z); o.w = f2bf(v.w);
        xb4[i] = o;
        return;
    }
    b -= 4096;
    if (b < 3072)       wtrans_body(tile, q_a_w,  W1,                  2048, 1536, b % 64, b / 64, tid);
    else if ((b -= 3072) < 1280) wtrans_body(tile, kv_a_w, W1 + 1536ULL * 2048, 2048, 576,  b % 64, b / 64, tid);
    else if ((b -= 1280) < 4608) wtrans_body(tile, q_b_w,  qbwt,       1536, 3072, b % 48, b / 48, tid);
    else if ((b -= 4608) < 2048) wtrans_body(tile, kv_b_w, kvbwt,      512,  4096, b % 16, b / 16, tid);
    else { b -= 2048;            wtrans_body(tile, o_w,    owt,        2048, 2048, b % 64, b / 64, tid); }
}

// ---------------------------------------------------------------------------
// norm_k: fused q_a rmsnorm (1536 cols, in-place) + kv_a norm/rope/cache.
// ---------------------------------------------------------------------------
__global__ __launch_bounds__(256)
void norm_k(u16* __restrict__ qkv, const float* __restrict__ q_ln,
            const float* __restrict__ kv_ln, const int* __restrict__ pos_ids,
            const float* __restrict__ cosb, const float* __restrict__ sinb,
            float* __restrict__ kvout, u16* __restrict__ cnb,
            u16* __restrict__ kpe)
{
    const int s = blockIdx.x, tid = threadIdx.x;
    u16* row = qkv + (long)s * 2176;
    u16* row2 = row + 1536;
    __shared__ float red[8];
    float sum = 0.f;
    for (int d = tid; d < 1536; d += 256) { float v = bf2f(row[d]); sum += v * v; }
    #pragma unroll
    for (int o = 32; o; o >>= 1) sum += __shfl_xor(sum, o, 64);
    if ((tid & 63) == 0) red[tid >> 6] = sum;
    float sum2 = 0.f;
    for (int d = tid; d < 512; d += 256) { float v = bf2f(row2[d]); sum2 += v * v; }
    #pragma unroll
    for (int o = 32; o; o >>= 1) sum2 += __shfl_xor(sum2, o, 64);
    if ((tid & 63) == 0) red[4 + (tid >> 6)] = sum2;
    __syncthreads();
    sum  = red[0] + red[1] + red[2] + red[3];
    sum2 = red[4] + red[5] + red[6] + red[7];
    const float sc1 = rsqrtf(sum / 1536.f + EPS);
    const float sc2 = rsqrtf(sum2 / 512.f + EPS);
    for (int d = tid; d < 1536; d += 256)
        row[d] = f2bf(bf2f(row[d]) * sc1 * q_ln[d]);
    for (int d = tid; d < 512; d += 256) {
        float v = bf2f(row2[d]) * sc2 * kv_ln[d];
        kvout[(long)s * 576 + d] = v;
        cnb[(long)s * 512 + d] = f2bf(v);
    }
    if (tid < 32) {
        int p = pos_ids[s];
        float x0 = bf2f(row2[512 + 2 * tid]);
        float x1 = bf2f(row2[512 + 2 * tid + 1]);
        float c1 = cosb[p * 64 + tid], s1 = sinb[p * 64 + tid];
        float c2 = cosb[p * 64 + 32 + tid], s2 = sinb[p * 64 + 32 + tid];
        float lo = x0 * c1 - x1 * s1;
        float hi = x1 * c2 + x0 * s2;
        kvout[(long)s * 576 + 512 + tid] = lo;
        kvout[(long)s * 576 + 544 + tid] = hi;
        kpe[(long)s * 64 + tid] = f2bf(lo);
        kpe[(long)s * 64 + 32 + tid] = f2bf(hi);
    }
}

// ---------------------------------------------------------------------------
// post_k: fused qrope ([0,2048) blocks) + vtrans ([2048,6144) blocks).
// vtrans s-axis permuted within 32-blocks so flash PV reads b128:
// new position quad*8 + half*4 + i  <->  s = half*16 + quad*4 + i.
// ---------------------------------------------------------------------------
__global__ __launch_bounds__(256)
void post_k(const u16* __restrict__ qb, const int* __restrict__ pos_ids,
            const float* __restrict__ cosb, const float* __restrict__ sinb,
            u16* __restrict__ query, const u16* __restrict__ kv,
            u16* __restrict__ vt)
{
    __shared__ u16 tile[32][33];
    const int tid = threadIdx.x;
    int b = (int)blockIdx.x;
    if (b < 2048) {
        const int s = b;
        const u16* row = qb + (long)s * 3072;
        {   // nope part: 16 heads x 16 chunks of 8, scaled
            int h = tid >> 4, c = tid & 15;
            const u16* src = &row[h * QHEAD + c * 8];
            u16* dst = &query[((long)(h * S_LEN + s)) * QHEAD + c * 8];
            ushort4 a = *(const ushort4*)src;
            ushort4 bb = *(const ushort4*)(src + 4);
            ushort4 oa, ob;
            oa.x = f2bf(bf2f(a.x) * QSCALE_LOG2E); oa.y = f2bf(bf2f(a.y) * QSCALE_LOG2E);
            oa.z = f2bf(bf2f(a.z) * QSCALE_LOG2E); oa.w = f2bf(bf2f(a.w) * QSCALE_LOG2E);
            ob.x = f2bf(bf2f(bb.x) * QSCALE_LOG2E); ob.y = f2bf(bf2f(bb.y) * QSCALE_LOG2E);
            ob.z = f2bf(bf2f(bb.z) * QSCALE_LOG2E); ob.w = f2bf(bf2f(bb.w) * QSCALE_LOG2E);
            *(ushort4*)dst = oa;
            *(ushort4*)(dst + 4) = ob;
        }
        int p = pos_ids[s];
        for (int idx = tid; idx < 512; idx += 256) {
            int h = idx >> 5, i = idx & 31;
            float x0 = bf2f(row[h * QHEAD + 128 + 2 * i]);
            float x1 = bf2f(row[h * QHEAD + 128 + 2 * i + 1]);
            float c1 = cosb[p * 64 + i], s1 = sinb[p * 64 + i];
            float c2 = cosb[p * 64 + 32 + i], s2 = sinb[p * 64 + 32 + i];
            u16* qr = query + ((long)(h * S_LEN + s)) * QHEAD;
            qr[128 + i] = f2bf((x0 * c1 - x1 * s1) * QSCALE_LOG2E);
            qr[160 + i] = f2bf((x1 * c2 + x0 * s2) * QSCALE_LOG2E);
        }
    } else {
        b -= 2048;
        const int s0 = (b & 63) * 32, d0 = ((b >> 6) & 3) * 32, h = b >> 8;
        const int tx = tid & 31, ty = tid >> 5;
        #pragma unroll
        for (int jj = 0; jj < 32; jj += 8)
            tile[ty + jj][tx] = kv[(long)(s0 + ty + jj) * 4096 + h * 256 + 128 + d0 + tx];
        __syncthreads();
        const int txp = ((tx >> 2) & 3) * 8 + (tx >> 4) * 4 + (tx & 3);
        #pragma unroll
        for (int jj = 0; jj < 32; jj += 8)
            vt[(long)(h * 128 + d0 + ty + jj) * S_LEN + s0 + txp] = tile[tx][ty + jj];
    }
}

// ---------------------------------------------------------------------------
extern "C" void kernel_launch(void* const* d_in, const int* in_sizes, int n_in,
                              void* d_out, int out_size, void* d_ws, size_t ws_size,
                              hipStream_t stream)
{
    const float* x      = (const float*)d_in[0];
    const int*   posid  = (const int*)d_in[2];
    const float* cosb   = (const float*)d_in[3];
    const float* sinb   = (const float*)d_in[4];
    const float* q_a_w  = (const float*)d_in[5];
    const float* q_a_ln = (const float*)d_in[6];
    const float* q_b_w  = (const float*)d_in[7];
    const float* kv_a_w = (const float*)d_in[8];
    const float* kv_a_ln= (const float*)d_in[9];
    const float* kv_b_w = (const float*)d_in[10];
    const float* o_w    = (const float*)d_in[11];

    float* out    = (float*)d_out;
    float* kv_out = out + (size_t)2048 * 2048;

    char* ws = (char*)d_ws;
    size_t off = 0;
    auto alloc = [&](size_t bytes) { char* p = ws + off; off += (bytes + 255) & ~(size_t)255; return p; };
    u16* xb    = (u16*)alloc(2048ULL * 2048 * 2);
    u16* W1    = (u16*)alloc(2176ULL * 2048 * 2);   // [q_a^T ; kv_a^T(pad 640)]
    u16* qbwt  = (u16*)alloc(3072ULL * 1536 * 2);
    u16* kvbwt = (u16*)alloc(4096ULL * 512 * 2);
    u16* owt   = (u16*)alloc(2048ULL * 2048 * 2);
    u16* qkv_a = (u16*)alloc(2048ULL * 2176 * 2);   // [q_a(1536) | ckv(640)]
    u16* qbuf  = (u16*)alloc(2048ULL * 3072 * 2);
    u16* query = (u16*)alloc(16ULL * 2048 * 192 * 2);
    u16* cnb   = (u16*)alloc(2048ULL * 512 * 2);
    u16* kpe   = (u16*)alloc(2048ULL * 64 * 2);
    u16* kvbuf = (u16*)alloc(2048ULL * 4096 * 2);
    u16* vt    = (u16*)alloc(16ULL * 128 * 2048 * 2);
    u16* ao    = (u16*)alloc(2048ULL * 2048 * 2);
    (void)ws_size; (void)in_sizes; (void)n_in; (void)out_size;

    dim3 blk(256);

    // 0) fused conversions / weight transposes (19200 blocks)
    prep_k<<<dim3(19200), blk, 0, stream>>>(
        (const float4*)x, (ushort4*)xb, q_a_w, kv_a_w, q_b_w, kv_b_w, o_w,
        W1, qbwt, kvbwt, owt);

    // 1) [q_a | ckv] = x @ [q_a_w | kv_a_w]  (merged, N=2176)
    //    grid (16,17): x -> tm (XCD-pinned, chunk 2), y -> tn
    gemm_bt<0, 1><<<dim3(16, 17), blk, 0, stream>>>(
        xb, W1, qkv_a, 2048, 2048, 2048, 2176, 2);

    // 2) fused rmsnorm + kv norm/rope/cache
    norm_k<<<dim3(2048), blk, 0, stream>>>(qkv_a, q_a_ln, kv_a_ln, posid,
                                           cosb, sinb, kv_out, cnb, kpe);

    // 3) q = q_a_norm @ q_b_w  AND  kv = c_norm @ kv_b_w  (one dispatch,
    //    XCD-pinned tn slabs: chunk 3 for nx=24, chunk 4 for nx=32)
    gemm_bt_dual<<<dim3(32, 16, 2), blk, 0, stream>>>(
        qkv_a, qbwt, qbuf, 1536, 2176, 1536, 3072, 24,
        cnb, kvbwt, kvbuf, 512, 512, 512, 4096, 32);

    // 4) fused qrope + value transpose
    post_k<<<dim3(6144), blk, 0, stream>>>(qbuf, posid, cosb, sinb, query, kvbuf, vt);

    // 5) fused flash attention (4-wave, pipelined) -> ao bf16 [S][H*128]
    flash_attn<<<dim3(512), dim3(256), 0, stream>>>(query, kvbuf, kpe, vt, ao);

    // 6) out = ao @ o_w (fp32), grid (16,16): x -> tn (XCD-pinned, chunk 2)
    gemm_bt<1, 0><<<dim3(16, 16), blk, 0, stream>>>(
        ao, owt, out, 2048, 2048, 2048, 2048, 2);
}

// Round 11
// 390.641 us; speedup vs baseline: 1.0948x; 1.0118x over previous
//
#include <hip/hip_runtime.h>

typedef unsigned short u16;
typedef __bf16 bf16x8 __attribute__((ext_vector_type(8)));
typedef short s16x4 __attribute__((ext_vector_type(4)));
typedef short s16x8 __attribute__((ext_vector_type(8)));
typedef float f32x4 __attribute__((ext_vector_type(4)));

#define S_LEN 2048
#define NHEAD 16
#define QHEAD 192
#define EPS 1e-6f
#define ATTN_SCALE 0.07216878364870323f   /* 192^-0.5 */
#define QSCALE_LOG2E 0.10412011228586118f /* ATTN_SCALE * log2(e) */

__device__ __forceinline__ u16 f2bf(float f) {
    unsigned u = __builtin_bit_cast(unsigned, f);
    u = (u + 0x7FFFu + ((u >> 16) & 1u)) >> 16;
    return (u16)u;
}
__device__ __forceinline__ float bf2f(u16 h) {
    unsigned u = ((unsigned)h) << 16;
    return __builtin_bit_cast(float, u);
}

__device__ __forceinline__ void gl_lds16(const u16* g, u16* l) {
    __builtin_amdgcn_global_load_lds(
        (const __attribute__((address_space(1))) unsigned int*)g,
        (__attribute__((address_space(3))) unsigned int*)l,
        16, 0, 0);
}

#if defined(__has_builtin) && __has_builtin(__builtin_amdgcn_mfma_f32_16x16x16bf16_1k)
__device__ __forceinline__ f32x4 mfma16(s16x4 a, s16x4 b, f32x4 c) {
    return __builtin_amdgcn_mfma_f32_16x16x16bf16_1k(a, b, c, 0, 0, 0);
}
#else
__device__ __forceinline__ f32x4 mfma16(s16x4 a, s16x4 b, f32x4 c) {
    asm volatile("v_mfma_f32_16x16x16_bf16 %0, %1, %2, %0"
                 : "+v"(c) : "v"(a), "v"(b));
    return c;
}
#endif

// ---------------------------------------------------------------------------
// bf16 GEMM core:  C[M][N] = A[M][K] @ Bt[N][K]^T
// 4-wave (256-thread) blocks, 128x128 tile, wave-tile 64x64, BK=64 per
// iteration, double-buffered prefetch with end-of-iter vmcnt(0)+s_barrier.
// LDS 2 x 32KB = 64KB -> 2 blocks/CU. Buffer select by offset arithmetic
// (gfx950 addrspace-select miscompile with ternary LDS ptrs into gl_lds).
// sched_barrier(0) fences around waits per rule #18.
// Round-10 post-mortem: per-iteration mechanics are exhausted (occupancy,
// counted vmcnt, BK, XCD-pin all ~flat). The remaining lever is DISPATCH
// FILL: grids of 256-272 blocks (1/CU) leave no co-resident block to hide
// the iter latency chain. Hence split-K below.
// ---------------------------------------------------------------------------
template <int CF32>
__device__ __forceinline__ void gemm_core(
    u16* __restrict__ smem,
    const u16* __restrict__ A, const u16* __restrict__ B, void* __restrict__ Cv,
    int K, int lda, int ldb, int ldc, int tm, int tn)
{
    const int tid = threadIdx.x;
    const int w = tid >> 6, lane = tid & 63;
    const int q = lane >> 4, r = lane & 15;

    const int lr = lane & 15;
    const int lc = (lane >> 4) * 8;
    // wave w stages A rows [w*32,+32) and B rows [w*32,+32), 2 k-chunks each
    const u16* ga0 = A + (long)(tm * 128 + w * 32 + lr) * lda + lc;
    const u16* ga1 = ga0 + 16 * (long)lda;
    const u16* gb0 = B + (long)(tn * 128 + w * 32 + lr) * ldb + lc;
    const u16* gb1 = gb0 + 16 * (long)ldb;
    const int sa0 = w * 1024, sa1 = sa0 + 512;
    const int sb0 = 4096 + w * 1024, sb1 = sb0 + 512;
    // buffer = 16384 u16 (32KB): sub-buf kk at +kk*8192 (A [0,4096), B [4096,8192))

    f32x4 acc[4][4] = {};
    const int wm = w >> 1;      // 64-row half
    const int wn = w & 1;       // 64-col half
    const int n = K >> 6;       // BK=64 iterations (K % 64 == 0 for all uses)

    // prologue: stage iter 0 (8 loads/wave)
    gl_lds16(ga0, smem + sa0);
    gl_lds16(ga1, smem + sa1);
    gl_lds16(gb0, smem + sb0);
    gl_lds16(gb1, smem + sb1);
    gl_lds16(ga0 + 32, smem + 8192 + sa0);
    gl_lds16(ga1 + 32, smem + 8192 + sa1);
    gl_lds16(gb0 + 32, smem + 8192 + sb0);
    gl_lds16(gb1 + 32, smem + 8192 + sb1);
    asm volatile("s_waitcnt vmcnt(0)" ::: "memory");
    __builtin_amdgcn_sched_barrier(0);
    __builtin_amdgcn_s_barrier();
    __builtin_amdgcn_sched_barrier(0);

    for (int t = 0; t < n; ++t) {
        u16* const cur = smem + (t & 1) * 16384;
        u16* const nxt = smem + ((t + 1) & 1) * 16384;
        if (t + 1 < n) {        // prefetch next BK=64 tile (full iter to land)
            const long k1 = (long)(t + 1) << 6;
            gl_lds16(ga0 + k1, nxt + sa0);
            gl_lds16(ga1 + k1, nxt + sa1);
            gl_lds16(gb0 + k1, nxt + sb0);
            gl_lds16(gb1 + k1, nxt + sb1);
            gl_lds16(ga0 + k1 + 32, nxt + 8192 + sa0);
            gl_lds16(ga1 + k1 + 32, nxt + 8192 + sa1);
            gl_lds16(gb0 + k1 + 32, nxt + 8192 + sb0);
            gl_lds16(gb1 + k1 + 32, nxt + 8192 + sb1);
        }
        #pragma unroll
        for (int kk = 0; kk < 2; ++kk) {
            u16* const sub = cur + kk * 8192;
            bf16x8 af[4], bv[4];
            #pragma unroll
            for (int mt = 0; mt < 4; ++mt)
                af[mt] = *(const bf16x8*)&sub[(wm * 4 + mt) * 512 + lane * 8];
            #pragma unroll
            for (int nt = 0; nt < 4; ++nt)
                bv[nt] = *(const bf16x8*)&sub[4096 + (wn * 4 + nt) * 512 + lane * 8];
            #pragma unroll
            for (int mt = 0; mt < 4; ++mt)
                #pragma unroll
                for (int nt = 0; nt < 4; ++nt)
                    acc[mt][nt] = __builtin_amdgcn_mfma_f32_16x16x32_bf16(
                        af[mt], bv[nt], acc[mt][nt], 0, 0, 0);
        }
        if (t + 1 < n) {
            asm volatile("s_waitcnt vmcnt(0)" ::: "memory");
            __builtin_amdgcn_sched_barrier(0);
            __builtin_amdgcn_s_barrier();
            __builtin_amdgcn_sched_barrier(0);
        }
    }

    const int row0 = tm * 128 + wm * 64 + q * 4;
    const int col0 = tn * 128 + wn * 64 + r;
    if (CF32) {
        float* C = (float*)Cv;
        #pragma unroll
        for (int mt = 0; mt < 4; ++mt)
            #pragma unroll
            for (int i = 0; i < 4; ++i) {
                long rb = (long)(row0 + mt * 16 + i) * ldc + col0;
                #pragma unroll
                for (int nt = 0; nt < 4; ++nt)
                    C[rb + nt * 16] = acc[mt][nt][i];
            }
    } else {
        u16* C = (u16*)Cv;
        #pragma unroll
        for (int mt = 0; mt < 4; ++mt)
            #pragma unroll
            for (int i = 0; i < 4; ++i) {
                long rb = (long)(row0 + mt * 16 + i) * ldc + col0;
                #pragma unroll
                for (int nt = 0; nt < 4; ++nt)
                    C[rb + nt * 16] = f2bf(acc[mt][nt][i]);
            }
    }
}

// Split-K x2 GEMM: z-slice b computes A[:, b*Kh:(b+1)*Kh] @ B[:, same]^T
// into its OWN fp32 partial buffer (Cz). Doubles block count -> ~2 blocks/CU
// queue depth (hides the iter latency chain) and halves the grid-remainder
// penalty. Partials are summed by the CONSUMER (norm_k / addout_k) - no
// atomics, fp32-exact.
__global__ __launch_bounds__(256, 2)
void gemm_ks(const u16* __restrict__ A, const u16* __restrict__ B,
             float* __restrict__ C0, float* __restrict__ C1,
             int Kh, int lda, int ldb, int ldc)
{
    __shared__ __align__(16) u16 smem[2 * 16384];
    const int z = blockIdx.z;
    float* C = z ? C1 : C0;
    gemm_core<1>(smem, A + (long)z * Kh, B + (long)z * Kh, C,
                 Kh, lda, ldb, ldc, blockIdx.y, blockIdx.x);
}

// Two independent GEMMs in ONE dispatch (z selects). Early-exit blocks
// return before any barrier (block-uniform - no hang).
__global__ __launch_bounds__(256, 2)
void gemm_bt_dual(const u16* __restrict__ A0, const u16* __restrict__ B0,
                  void* __restrict__ C0, int K0, int lda0, int ldb0, int ldc0, int nx0,
                  const u16* __restrict__ A1, const u16* __restrict__ B1,
                  void* __restrict__ C1, int K1, int lda1, int ldb1, int ldc1, int nx1)
{
    __shared__ __align__(16) u16 smem[2 * 16384];
    if (blockIdx.z == 0) {
        if ((int)blockIdx.x >= nx0) return;
        gemm_core<0>(smem, A0, B0, C0, K0, lda0, ldb0, ldc0,
                     blockIdx.y, blockIdx.x);
    } else {
        if ((int)blockIdx.x >= nx1) return;
        gemm_core<0>(smem, A1, B1, C1, K1, lda1, ldb1, ldc1,
                     blockIdx.y, blockIdx.x);
    }
}

// out[i] += p[i]  (fp32 split-K merge for the final GEMM)
__global__ __launch_bounds__(256)
void addout_k(float4* __restrict__ out, const float4* __restrict__ p)
{
    int i = blockIdx.x * 256 + threadIdx.x;
    float4 a = out[i], b = p[i];
    a.x += b.x; a.y += b.y; a.z += b.z; a.w += b.w;
    out[i] = a;
}

// ---------------------------------------------------------------------------
// Flash attention, S^T formulation, double-buffered prefetch pipeline.
// Known-good round-5/7/9 config (66us): 4 waves x 16 q-rows, 256 threads,
// kv-tile 64, 2x40KB LDS (2 blocks/CU -> 8 waves/CU). Latency-bound;
// occupancy is its currency. PV reads conflict-free b128 via s-permuted vt.
// Maxless exp2-domain softmax. Grid 1D 512, complementary pairing.
// ---------------------------------------------------------------------------
template<int C0, int C1>
__device__ __forceinline__ void stage_tile(
    const u16* __restrict__ kvb, const u16* __restrict__ kpe,
    const u16* __restrict__ vt,
    u16* __restrict__ Kl, u16* __restrict__ Vl,
    int h, int t, int quad, int r)
{
    #pragma unroll
    for (int c = C0; c < C1; ++c) {
        if (c < 24) {
            const int mtk = c / 6, kc = c % 6;
            const int row = t * 64 + mtk * 16 + r;
            const u16* src = (kc < 4)
                ? kvb + (size_t)row * 4096 + h * 256 + kc * 32 + quad * 8
                : kpe + (size_t)row * 64 + (kc - 4) * 32 + quad * 8;
            gl_lds16(src, &Kl[c * 512]);
        } else {
            const int cv = c - 24, mtd = cv >> 1, sc = cv & 1;
            const u16* src = vt + ((size_t)h * 128 + mtd * 16 + r) * 2048
                             + t * 64 + sc * 32 + quad * 8;
            gl_lds16(src, &Vl[cv * 512]);
        }
    }
}

__device__ __forceinline__ void stage_dispatch(
    const u16* __restrict__ kvb, const u16* __restrict__ kpe,
    const u16* __restrict__ vt,
    u16* __restrict__ Kl, u16* __restrict__ Vl,
    int w, int h, int t, int quad, int r)
{
    if (w == 0)      stage_tile<0, 10>(kvb, kpe, vt, Kl, Vl, h, t, quad, r);
    else if (w == 1) stage_tile<10, 20>(kvb, kpe, vt, Kl, Vl, h, t, quad, r);
    else if (w == 2) stage_tile<20, 30>(kvb, kpe, vt, Kl, Vl, h, t, quad, r);
    else             stage_tile<30, 40>(kvb, kpe, vt, Kl, Vl, h, t, quad, r);
}

__device__ __forceinline__ void kv_tile_step(
    const u16* __restrict__ Kl, const u16* __restrict__ Vl,
    const bf16x8 (&Qf)[6], f32x4 (&Oacc)[8], float& lsum,
    int lane, int quad, int r, int kglob0, int qg, bool maskT)
{
    f32x4 Sacc[4];
    #pragma unroll
    for (int mtk = 0; mtk < 4; ++mtk)
        Sacc[mtk] = (f32x4){0.f, 0.f, 0.f, 0.f};
    #pragma unroll
    for (int kc = 0; kc < 6; ++kc)
        #pragma unroll
        for (int mtk = 0; mtk < 4; ++mtk) {
            bf16x8 Ak = *(const bf16x8*)&Kl[(mtk * 6 + kc) * 512 + lane * 8];
            Sacc[mtk] = __builtin_amdgcn_mfma_f32_16x16x32_bf16(
                Ak, Qf[kc], Sacc[mtk], 0, 0, 0);
        }
    #pragma unroll
    for (int sc = 0; sc < 2; ++sc) {
        s16x4 Pf[2];
        #pragma unroll
        for (int half = 0; half < 2; ++half) {
            const int kb = sc * 2 + half;
            const int kb0 = kglob0 + kb * 16 + quad * 4;
            #pragma unroll
            for (int i = 0; i < 4; ++i) {
                float pv = exp2f(Sacc[kb][i]);
                if (maskT && (kb0 + i > qg)) pv = 0.f;
                lsum += pv;
                Pf[half][i] = (short)f2bf(pv);
            }
        }
        #pragma unroll
        for (int mtd = 0; mtd < 8; ++mtd) {
            s16x8 Av8 = *(const s16x8*)&Vl[(mtd * 2 + sc) * 512 + quad * 128 + r * 8];
            s16x4 lo = __builtin_shufflevector(Av8, Av8, 0, 1, 2, 3);
            s16x4 hi = __builtin_shufflevector(Av8, Av8, 4, 5, 6, 7);
            Oacc[mtd] = mfma16(lo, Pf[0], Oacc[mtd]);
            Oacc[mtd] = mfma16(hi, Pf[1], Oacc[mtd]);
        }
    }
}

__global__ __launch_bounds__(256, 2)
void flash_attn(const u16* __restrict__ query, const u16* __restrict__ kvb,
                const u16* __restrict__ kpe, const u16* __restrict__ vt,
                u16* __restrict__ ao)
{
    const int tid = threadIdx.x;
    const int w = tid >> 6, lane = tid & 63;
    const int quad = lane >> 4, r = lane & 15;

    const int bid = (int)blockIdx.x;
    const int i = bid & 255;
    const int t_ = i >> 4;
    const int h = i & 15;
    const int j = (bid < 256) ? (31 - t_) : t_;

    const int q0 = j * 64;
    const int ntk = j + 1;

    __shared__ __align__(16) u16 smem[40960];   // 80KB: two 40KB tile buffers
    // buffer b at smem + b*20480: K = [0,12288) u16, V = [12288,20480) u16

    const int qg = q0 + w * 16 + r;   // this wave's q row (causal bound)

    bf16x8 Qf[6];
    #pragma unroll
    for (int kc = 0; kc < 6; ++kc)
        Qf[kc] = *(const bf16x8*)(query
            + ((size_t)h * S_LEN + q0 + w * 16 + r) * QHEAD
            + kc * 32 + quad * 8);

    f32x4 Oacc[8];
    #pragma unroll
    for (int mtd = 0; mtd < 8; ++mtd)
        Oacc[mtd] = (f32x4){0.f, 0.f, 0.f, 0.f};
    float lsum = 0.f;

    // prologue: stage tile 0 into buffer 0
    stage_dispatch(kvb, kpe, vt, smem, smem + 12288, w, h, 0, quad, r);
    __syncthreads();

    for (int t = 0; t < ntk; ++t) {
        u16* const curb = smem + (t & 1) * 20480;          // offset arith,
        u16* const nxtb = smem + ((t + 1) & 1) * 20480;    // no ptr select
        if (t + 1 < ntk)
            stage_dispatch(kvb, kpe, vt, nxtb, nxtb + 12288, w, h, t + 1, quad, r);
        kv_tile_step(curb, curb + 12288, Qf, Oacc, lsum,
                     lane, quad, r, t * 64, qg, t == ntk - 1);
        __syncthreads();
    }

    // epilogue: each wave owns its 16 q-rows; reduce lsum over quads only
    float l = lsum;
    l += __shfl_xor(l, 16, 64);
    l += __shfl_xor(l, 32, 64);
    const float inv = 1.0f / l;
    const int qrow = q0 + w * 16 + r;
    #pragma unroll
    for (int mtd = 0; mtd < 8; ++mtd) {
        ushort4 o;
        o.x = f2bf(Oacc[mtd][0] * inv);
        o.y = f2bf(Oacc[mtd][1] * inv);
        o.z = f2bf(Oacc[mtd][2] * inv);
        o.w = f2bf(Oacc[mtd][3] * inv);
        *(ushort4*)(ao + (size_t)qrow * 2048 + h * 128 + mtd * 16 + quad * 4) = o;
    }
}

// ---------------------------------------------------------------------------
// prep_k: fused input-convert + 5 weight transposes (was 6 dispatches).
// Flattened 1D grid of 19200 blocks x 256 threads; branches block-uniform.
// ---------------------------------------------------------------------------
__device__ __forceinline__ void wtrans_body(
    float (*tile)[33], const float* __restrict__ in, u16* __restrict__ out,
    int K, int N, int bx, int by, int tid)
{
    const int tx = tid & 31, ty = tid >> 5;   // 32 x 8
    const int k0 = bx * 32, n0 = by * 32;
    #pragma unroll
    for (int jj = 0; jj < 32; jj += 8) {
        int nn = n0 + tx;
        tile[ty + jj][tx] = (nn < N) ? in[(long)(k0 + ty + jj) * N + nn] : 0.0f;
    }
    __syncthreads();
    #pragma unroll
    for (int jj = 0; jj < 32; jj += 8)
        out[(long)(n0 + ty + jj) * K + k0 + tx] = f2bf(tile[tx][ty + jj]);
}

__global__ __launch_bounds__(256)
void prep_k(const float4* __restrict__ x4, ushort4* __restrict__ xb4,
            const float* __restrict__ q_a_w, const float* __restrict__ kv_a_w,
            const float* __restrict__ q_b_w, const float* __restrict__ kv_b_w,
            const float* __restrict__ o_w,
            u16* __restrict__ W1, u16* __restrict__ qbwt,
            u16* __restrict__ kvbwt, u16* __restrict__ owt)
{
    __shared__ float tile[32][33];
    const int tid = threadIdx.x;
    int b = (int)blockIdx.x;
    if (b < 4096) {
        int i = b * 256 + tid;     // exactly 1048576 float4s
        float4 v = x4[i];
        ushort4 o;
        o.x = f2bf(v.x); o.y = f2bf(v.y); o.z = f2bf(v.z); o.w = f2bf(v.w);
        xb4[i] = o;
        return;
    }
    b -= 4096;
    if (b < 3072)       wtrans_body(tile, q_a_w,  W1,                  2048, 1536, b % 64, b / 64, tid);
    else if ((b -= 3072) < 1280) wtrans_body(tile, kv_a_w, W1 + 1536ULL * 2048, 2048, 576,  b % 64, b / 64, tid);
    else if ((b -= 1280) < 4608) wtrans_body(tile, q_b_w,  qbwt,       1536, 3072, b % 48, b / 48, tid);
    else if ((b -= 4608) < 2048) wtrans_body(tile, kv_b_w, kvbwt,      512,  4096, b % 16, b / 16, tid);
    else { b -= 2048;            wtrans_body(tile, o_w,    owt,        2048, 2048, b % 64, b / 64, tid); }
}

// ---------------------------------------------------------------------------
// norm_k: fused q_a rmsnorm + kv_a norm/rope/cache, now also the split-K
// MERGE for gemm1: reads fp32 partials pa+pb, stages the summed row in LDS
// (single global pass), writes q_a_norm bf16 into qkv_a[0..1536) per row.
// ---------------------------------------------------------------------------
__global__ __launch_bounds__(256)
void norm_k(const float* __restrict__ pa, const float* __restrict__ pb,
            u16* __restrict__ qkv, const float* __restrict__ q_ln,
            const float* __restrict__ kv_ln, const int* __restrict__ pos_ids,
            const float* __restrict__ cosb, const float* __restrict__ sinb,
            float* __restrict__ kvout, u16* __restrict__ cnb,
            u16* __restrict__ kpe)
{
    const int s = blockIdx.x, tid = threadIdx.x;
    __shared__ float rowbuf[2176];
    __shared__ float red[8];
    const long base = (long)s * 2176;
    float sum1 = 0.f, sum2 = 0.f;
    for (int d = tid; d < 2176; d += 256) {
        float v = pa[base + d] + pb[base + d];
        rowbuf[d] = v;
        if (d < 1536)      sum1 += v * v;
        else if (d < 2048) sum2 += v * v;
    }
    #pragma unroll
    for (int o = 32; o; o >>= 1) {
        sum1 += __shfl_xor(sum1, o, 64);
        sum2 += __shfl_xor(sum2, o, 64);
    }
    if ((tid & 63) == 0) { red[tid >> 6] = sum1; red[4 + (tid >> 6)] = sum2; }
    __syncthreads();
    sum1 = red[0] + red[1] + red[2] + red[3];
    sum2 = red[4] + red[5] + red[6] + red[7];
    const float sc1 = rsqrtf(sum1 / 1536.f + EPS);
    const float sc2 = rsqrtf(sum2 / 512.f + EPS);
    for (int d = tid; d < 1536; d += 256)
        qkv[base + d] = f2bf(rowbuf[d] * sc1 * q_ln[d]);
    for (int d = tid; d < 512; d += 256) {
        float v = rowbuf[1536 + d] * sc2 * kv_ln[d];
        kvout[(long)s * 576 + d] = v;
        cnb[(long)s * 512 + d] = f2bf(v);
    }
    if (tid < 32) {
        int p = pos_ids[s];
        float x0 = rowbuf[2048 + 2 * tid];
        float x1 = rowbuf[2048 + 2 * tid + 1];
        float c1 = cosb[p * 64 + tid], s1 = sinb[p * 64 + tid];
        float c2 = cosb[p * 64 + 32 + tid], s2 = sinb[p * 64 + 32 + tid];
        float lo = x0 * c1 - x1 * s1;
        float hi = x1 * c2 + x0 * s2;
        kvout[(long)s * 576 + 512 + tid] = lo;
        kvout[(long)s * 576 + 544 + tid] = hi;
        kpe[(long)s * 64 + tid] = f2bf(lo);
        kpe[(long)s * 64 + 32 + tid] = f2bf(hi);
    }
}

// ---------------------------------------------------------------------------
// post_k: fused qrope ([0,2048) blocks) + vtrans ([2048,6144) blocks).
// vtrans s-axis permuted within 32-blocks so flash PV reads b128:
// new position quad*8 + half*4 + i  <->  s = half*16 + quad*4 + i.
// ---------------------------------------------------------------------------
__global__ __launch_bounds__(256)
void post_k(const u16* __restrict__ qb, const int* __restrict__ pos_ids,
            const float* __restrict__ cosb, const float* __restrict__ sinb,
            u16* __restrict__ query, const u16* __restrict__ kv,
            u16* __restrict__ vt)
{
    __shared__ u16 tile[32][33];
    const int tid = threadIdx.x;
    int b = (int)blockIdx.x;
    if (b < 2048) {
        const int s = b;
        const u16* row = qb + (long)s * 3072;
        {   // nope part: 16 heads x 16 chunks of 8, scaled
            int h = tid >> 4, c = tid & 15;
            const u16* src = &row[h * QHEAD + c * 8];
            u16* dst = &query[((long)(h * S_LEN + s)) * QHEAD + c * 8];
            ushort4 a = *(const ushort4*)src;
            ushort4 bb = *(const ushort4*)(src + 4);
            ushort4 oa, ob;
            oa.x = f2bf(bf2f(a.x) * QSCALE_LOG2E); oa.y = f2bf(bf2f(a.y) * QSCALE_LOG2E);
            oa.z = f2bf(bf2f(a.z) * QSCALE_LOG2E); oa.w = f2bf(bf2f(a.w) * QSCALE_LOG2E);
            ob.x = f2bf(bf2f(bb.x) * QSCALE_LOG2E); ob.y = f2bf(bf2f(bb.y) * QSCALE_LOG2E);
            ob.z = f2bf(bf2f(bb.z) * QSCALE_LOG2E); ob.w = f2bf(bf2f(bb.w) * QSCALE_LOG2E);
            *(ushort4*)dst = oa;
            *(ushort4*)(dst + 4) = ob;
        }
        int p = pos_ids[s];
        for (int idx = tid; idx < 512; idx += 256) {
            int h = idx >> 5, i = idx & 31;
            float x0 = bf2f(row[h * QHEAD + 128 + 2 * i]);
            float x1 = bf2f(row[h * QHEAD + 128 + 2 * i + 1]);
            float c1 = cosb[p * 64 + i], s1 = sinb[p * 64 + i];
            float c2 = cosb[p * 64 + 32 + i], s2 = sinb[p * 64 + 32 + i];
            u16* qr = query + ((long)(h * S_LEN + s)) * QHEAD;
            qr[128 + i] = f2bf((x0 * c1 - x1 * s1) * QSCALE_LOG2E);
            qr[160 + i] = f2bf((x1 * c2 + x0 * s2) * QSCALE_LOG2E);
        }
    } else {
        b -= 2048;
        const int s0 = (b & 63) * 32, d0 = ((b >> 6) & 3) * 32, h = b >> 8;
        const int tx = tid & 31, ty = tid >> 5;
        #pragma unroll
        for (int jj = 0; jj < 32; jj += 8)
            tile[ty + jj][tx] = kv[(long)(s0 + ty + jj) * 4096 + h * 256 + 128 + d0 + tx];
        __syncthreads();
        const int txp = ((tx >> 2) & 3) * 8 + (tx >> 4) * 4 + (tx & 3);
        #pragma unroll
        for (int jj = 0; jj < 32; jj += 8)
            vt[(long)(h * 128 + d0 + ty + jj) * S_LEN + s0 + txp] = tile[tx][ty + jj];
    }
}

// ---------------------------------------------------------------------------
extern "C" void kernel_launch(void* const* d_in, const int* in_sizes, int n_in,
                              void* d_out, int out_size, void* d_ws, size_t ws_size,
                              hipStream_t stream)
{
    const float* x      = (const float*)d_in[0];
    const int*   posid  = (const int*)d_in[2];
    const float* cosb   = (const float*)d_in[3];
    const float* sinb   = (const float*)d_in[4];
    const float* q_a_w  = (const float*)d_in[5];
    const float* q_a_ln = (const float*)d_in[6];
    const float* q_b_w  = (const float*)d_in[7];
    const float* kv_a_w = (const float*)d_in[8];
    const float* kv_a_ln= (const float*)d_in[9];
    const float* kv_b_w = (const float*)d_in[10];
    const float* o_w    = (const float*)d_in[11];

    float* out    = (float*)d_out;
    float* kv_out = out + (size_t)2048 * 2048;

    char* ws = (char*)d_ws;
    size_t off = 0;
    auto alloc = [&](size_t bytes) { char* p = ws + off; off += (bytes + 255) & ~(size_t)255; return p; };
    u16* xb    = (u16*)alloc(2048ULL * 2048 * 2);
    u16* W1    = (u16*)alloc(2176ULL * 2048 * 2);   // [q_a^T ; kv_a^T(pad 640)]
    u16* qbwt  = (u16*)alloc(3072ULL * 1536 * 2);
    u16* kvbwt = (u16*)alloc(4096ULL * 512 * 2);
    u16* owt   = (u16*)alloc(2048ULL * 2048 * 2);
    u16* qkv_a = (u16*)alloc(2048ULL * 2176 * 2);   // [q_a_norm(1536) | unused]
    u16* qbuf  = (u16*)alloc(2048ULL * 3072 * 2);
    u16* query = (u16*)alloc(16ULL * 2048 * 192 * 2);
    u16* cnb   = (u16*)alloc(2048ULL * 512 * 2);
    u16* kpe   = (u16*)alloc(2048ULL * 64 * 2);
    u16* kvbuf = (u16*)alloc(2048ULL * 4096 * 2);
    u16* vt    = (u16*)alloc(16ULL * 128 * 2048 * 2);
    u16* ao    = (u16*)alloc(2048ULL * 2048 * 2);
    (void)ws_size; (void)in_sizes; (void)n_in; (void)out_size;

    // Split-K partial buffers OVERLAID on regions that are dead at use time:
    //  - gemm1 partials (fp32 [2048][2176] = 17.8MB each) live in the
    //    qbuf+query region (25.2MB) and kvbuf+vt region (33.6MB): those are
    //    first written at the dual/post stage, AFTER norm_k consumed them.
    //  - gemm5 partial p5 (fp32 [2048][2048] = 16.8MB) lives in xb+W1
    //    (17.3MB): dead after gemm1.
    float* g1p0 = (float*)qbuf;
    float* g1p1 = (float*)kvbuf;
    float* g5p  = (float*)xb;

    dim3 blk(256);

    // 0) fused conversions / weight transposes (19200 blocks)
    prep_k<<<dim3(19200), blk, 0, stream>>>(
        (const float4*)x, (ushort4*)xb, q_a_w, kv_a_w, q_b_w, kv_b_w, o_w,
        W1, qbwt, kvbwt, owt);

    // 1) [q_a | ckv] = x @ [q_a_w | kv_a_w]  (merged, N=2176), split-K x2:
    //    z=0 -> K[0,1024) into g1p0, z=1 -> K[1024,2048) into g1p1.
    //    544 blocks (~2.1/CU) instead of 272 (~1.06/CU).
    gemm_ks<<<dim3(17, 16, 2), blk, 0, stream>>>(
        xb, W1, g1p0, g1p1, 1024, 2048, 2048, 2176);

    // 2) fused split-K merge + rmsnorm + kv norm/rope/cache
    norm_k<<<dim3(2048), blk, 0, stream>>>(g1p0, g1p1, qkv_a, q_a_ln, kv_a_ln,
                                           posid, cosb, sinb, kv_out, cnb, kpe);

    // 3) q = q_a_norm @ q_b_w  AND  kv = c_norm @ kv_b_w  (one dispatch)
    gemm_bt_dual<<<dim3(32, 16, 2), blk, 0, stream>>>(
        qkv_a, qbwt, qbuf, 1536, 2176, 1536, 3072, 24,
        cnb, kvbwt, kvbuf, 512, 512, 512, 4096, 32);

    // 4) fused qrope + value transpose
    post_k<<<dim3(6144), blk, 0, stream>>>(qbuf, posid, cosb, sinb, query, kvbuf, vt);

    // 5) fused flash attention (4-wave, pipelined) -> ao bf16 [S][H*128]
    flash_attn<<<dim3(512), dim3(256), 0, stream>>>(query, kvbuf, kpe, vt, ao);

    // 6) out = ao @ o_w (fp32), split-K x2: z=0 -> g5p, z=1 -> out;
    //    then out += g5p. 512 blocks (2/CU) instead of 256 (1/CU).
    gemm_ks<<<dim3(16, 16, 2), blk, 0, stream>>>(
        ao, owt, g5p, out, 1024, 2048, 2048, 2048);
    addout_k<<<dim3(4096), blk, 0, stream>>>((float4*)out, (const float4*)g5p);
}